// Round 1
// baseline (3227.587 us; speedup 1.0000x reference)
//
#include <hip/hip_runtime.h>
#include <math.h>

// Problem constants
#define BB 64
#define TT 32
#define MM 64
#define BT 2048            // B*T
#define GNN 256
#define NHEAD 4
#define CDIM 64
#define TEMPD 256
#define NHT 8
#define HDT 32
#define OUTD 512

__device__ inline float dot4(const float4 a, const float4 b) {
    return fmaf(a.x, b.x, fmaf(a.y, b.y, fmaf(a.z, b.z, a.w * b.w)));
}

__device__ inline void fma_tile(float4& a, const float4 xv, const float4 w0,
                                const float4 w1, const float4 w2, const float4 w3) {
    a.x = fmaf(xv.x, w0.x, fmaf(xv.y, w1.x, fmaf(xv.z, w2.x, fmaf(xv.w, w3.x, a.x))));
    a.y = fmaf(xv.x, w0.y, fmaf(xv.y, w1.y, fmaf(xv.z, w2.y, fmaf(xv.w, w3.y, a.y))));
    a.z = fmaf(xv.x, w0.z, fmaf(xv.y, w1.z, fmaf(xv.z, w2.z, fmaf(xv.w, w3.z, a.z))));
    a.w = fmaf(xv.x, w0.w, fmaf(xv.y, w1.w, fmaf(xv.z, w2.w, fmaf(xv.w, w3.w, a.w))));
}

// block-wide (256 threads) sum of two values via wave shuffle + LDS
__device__ inline void block_reduce2(float& a, float& b, float* red) {
    #pragma unroll
    for (int off = 32; off; off >>= 1) {
        a += __shfl_xor(a, off);
        b += __shfl_xor(b, off);
    }
    int wid = threadIdx.x >> 6;
    int lane = threadIdx.x & 63;
    if (lane == 0) { red[wid] = a; red[4 + wid] = b; }
    __syncthreads();
    a = red[0] + red[1] + red[2] + red[3];
    b = red[4] + red[5] + red[6] + red[7];
    __syncthreads();
}

// ---------------------------------------------------------------------------
// Transpose 256x256 W (row-major out,in) -> WT (in, out) for coalesced reads
__global__ __launch_bounds__(256) void k_transpose256(const float* __restrict__ W,
                                                      float* __restrict__ WT) {
    int i = blockIdx.x;     // 0..255 (input index)
    int g = threadIdx.x;    // 0..255 (output index)
    WT[i * 256 + g] = W[g * 256 + i];
}

// ---------------------------------------------------------------------------
// Geometry: per (b,t) graph, eattr (with self-loop averaging) + full_adj.
// geo[(bt*64+d)*64+s] = (dist, relx, rely, full_adj) with rel = pos[d]-pos[s]
__global__ __launch_bounds__(64) void k_geo(const float* __restrict__ boxes,
                                            const float* __restrict__ mask,
                                            float4* __restrict__ geo) {
    int bt = blockIdx.x;
    __shared__ float px[64], py[64], vm[64];
    int m = threadIdx.x;
    const float* bx = boxes + (size_t)(bt * 64 + m) * 5;
    px[m] = bx[1];
    py[m] = bx[2];
    vm[m] = mask[bt * 64 + m];
    __syncthreads();
    int d = m;
    bool vd = vm[d] > 0.5f;
    float deg = 0.f, s0 = 0.f, s1 = 0.f, s2 = 0.f;
    for (int s = 0; s < 64; s++) {
        float rx = px[d] - px[s], ry = py[d] - py[s];
        float dist = sqrtf(fmaxf(rx * rx + ry * ry, 1e-12f));
        bool adj = vd && (vm[s] > 0.5f) && (dist < 0.3f) && (s != d);
        if (adj) { deg += 1.f; s0 += dist; s1 += rx; s2 += ry; }
    }
    float dg = fmaxf(deg, 1.f);
    float l0 = s0 / dg, l1 = s1 / dg, l2 = s2 / dg;
    float4* row = geo + (size_t)(bt * 64 + d) * 64;
    for (int s = 0; s < 64; s++) {
        float rx = px[d] - px[s], ry = py[d] - py[s];
        float dist = sqrtf(fmaxf(rx * rx + ry * ry, 1e-12f));
        bool adj = vd && (vm[s] > 0.5f) && (dist < 0.3f) && (s != d);
        float4 v;
        if (adj)            v = make_float4(dist, rx, ry, 1.f);
        else if (s == d)    v = make_float4(l0, l1, l2, vd ? 1.f : 0.f);
        else                v = make_float4(0.f, 0.f, 0.f, 0.f);
        row[s] = v;
    }
}

// ---------------------------------------------------------------------------
// in_proj: x[bt,m,:] = (feats[bt,m,:] @ WT) + b, masked by valid.
// One block per (b,t); 256 threads; 16m x 4k register micro-tiles.
__global__ __launch_bounds__(256) void k_inproj(const float* __restrict__ feats,
                                                const float* __restrict__ WT,
                                                const float* __restrict__ bias,
                                                const float* __restrict__ mask,
                                                float* __restrict__ xbuf) {
    int bt = blockIdx.x;
    size_t base = (size_t)bt * 64 * 256;
    __shared__ float Fs[64 * 260];
    for (int idx = threadIdx.x; idx < 64 * 256; idx += 256) {
        int m = idx >> 8, c = idx & 255;
        Fs[m * 260 + c] = feats[base + idx];
    }
    __syncthreads();
    int lane = threadIdx.x & 63, w = threadIdx.x >> 6;
    float4 bv = *(const float4*)&bias[4 * lane];
    float4 acc[16];
    #pragma unroll
    for (int ml = 0; ml < 16; ml++) acc[ml] = bv;
    for (int i = 0; i < 256; i += 4) {
        float4 w0 = *(const float4*)&WT[(i + 0) * 256 + 4 * lane];
        float4 w1 = *(const float4*)&WT[(i + 1) * 256 + 4 * lane];
        float4 w2 = *(const float4*)&WT[(i + 2) * 256 + 4 * lane];
        float4 w3 = *(const float4*)&WT[(i + 3) * 256 + 4 * lane];
        #pragma unroll
        for (int ml = 0; ml < 16; ml++) {
            int m = w * 16 + ml;
            float4 xv = *(const float4*)&Fs[m * 260 + i];
            fma_tile(acc[ml], xv, w0, w1, w2, w3);
        }
    }
    #pragma unroll
    for (int ml = 0; ml < 16; ml++) {
        int m = w * 16 + ml;
        float vmv = mask[bt * 64 + m] > 0.5f ? 1.f : 0.f;
        float4 o = acc[ml];
        o.x *= vmv; o.y *= vmv; o.z *= vmv; o.w *= vmv;
        *(float4*)&xbuf[base + m * 256 + 4 * lane] = o;
    }
}

// ---------------------------------------------------------------------------
// Fused GAT layer: one block per (b,t). Phases:
//  A: load x tile -> LDS.  B: h = x @ linW (regs).  C: h -> LDS (overwrite x).
//  D: a_src/a_dst/w_e.  E: per-head (wave) softmax attention + message (dest loop).
//  F: LN(msg + bias + x_old) * s + b, relu, write x in place.
__global__ __launch_bounds__(256) void k_gat(float* __restrict__ xbuf,
                                             const float4* __restrict__ geo,
                                             const float* __restrict__ linW,
                                             const float* __restrict__ edgeW,
                                             const float* __restrict__ attS,
                                             const float* __restrict__ attD,
                                             const float* __restrict__ attE,
                                             const float* __restrict__ bias,
                                             const float* __restrict__ lns,
                                             const float* __restrict__ lnb) {
    int bt = blockIdx.x;
    size_t base = (size_t)bt * 64 * 256;
    __shared__ float HS[64 * 260];          // x tile, then h tile, then msg tile
    __shared__ float asrcS[256], adstS[256], wES[12], alphaS[256];
    int tid = threadIdx.x;
    int lane = tid & 63, w = tid >> 6;

    // Phase A
    for (int idx = tid; idx < 64 * 256; idx += 256) {
        int m = idx >> 8, c = idx & 255;
        HS[m * 260 + c] = xbuf[base + idx];
    }
    __syncthreads();

    // Phase B: h[m][k] = sum_g x[m][g] * linW[g][k]   (linW already in->out layout)
    float4 acc[16];
    #pragma unroll
    for (int ml = 0; ml < 16; ml++) acc[ml] = make_float4(0.f, 0.f, 0.f, 0.f);
    for (int i = 0; i < 256; i += 4) {
        float4 w0 = *(const float4*)&linW[(i + 0) * 256 + 4 * lane];
        float4 w1 = *(const float4*)&linW[(i + 1) * 256 + 4 * lane];
        float4 w2 = *(const float4*)&linW[(i + 2) * 256 + 4 * lane];
        float4 w3 = *(const float4*)&linW[(i + 3) * 256 + 4 * lane];
        #pragma unroll
        for (int ml = 0; ml < 16; ml++) {
            int m = w * 16 + ml;
            float4 xv = *(const float4*)&HS[m * 260 + i];
            fma_tile(acc[ml], xv, w0, w1, w2, w3);
        }
    }
    __syncthreads();   // all reads of x tile done

    // Phase C
    #pragma unroll
    for (int ml = 0; ml < 16; ml++) {
        int m = w * 16 + ml;
        *(float4*)&HS[m * 260 + 4 * lane] = acc[ml];
    }
    __syncthreads();

    // Phase D: a_src/a_dst per (m, head); w_e per (e, head)
    {
        int mD = lane, hh = w;
        float s1 = 0.f, s2 = 0.f;
        const float* pS = attS + hh * 64;
        const float* pD = attD + hh * 64;
        #pragma unroll
        for (int c = 0; c < 64; c += 4) {
            float4 hv = *(const float4*)&HS[mD * 260 + hh * 64 + c];
            float4 a1 = *(const float4*)&pS[c];
            float4 a2 = *(const float4*)&pD[c];
            s1 += dot4(hv, a1);
            s2 += dot4(hv, a2);
        }
        asrcS[hh * 64 + mD] = s1;
        adstS[hh * 64 + mD] = s2;
        if (tid < 12) {
            int e = tid >> 2, h2 = tid & 3;
            float sm = 0.f;
            for (int c = 0; c < 64; c++)
                sm += edgeW[e * 256 + h2 * 64 + c] * attE[h2 * 64 + c];
            wES[e * 4 + h2] = sm;
        }
    }
    __syncthreads();

    // Phase E: wave w = head h; lane = source s for logits, channel c for msg.
    {
        int h = w;
        float hreg[64];
        #pragma unroll
        for (int ss = 0; ss < 64; ss++) hreg[ss] = HS[ss * 260 + h * 64 + lane];
        __syncthreads();   // all h reads done; HS memory now free for msg

        float we0 = wES[0 * 4 + h], we1 = wES[1 * 4 + h], we2 = wES[2 * 4 + h];
        float a_s = asrcS[h * 64 + lane];
        float bv = bias[h * 64 + lane];
        const float4* grow = geo + (size_t)bt * 64 * 64;
        for (int d = 0; d < 64; d++) {
            float4 g = grow[d * 64 + lane];
            float logit = a_s + adstS[h * 64 + d] + g.x * we0 + g.y * we1 + g.z * we2;
            logit = logit >= 0.f ? logit : 0.2f * logit;
            logit = g.w > 0.5f ? logit : -1e9f;
            float mx = logit;
            #pragma unroll
            for (int off = 32; off; off >>= 1) mx = fmaxf(mx, __shfl_xor(mx, off));
            float e = __expf(logit - mx);
            float sm = e;
            #pragma unroll
            for (int off = 32; off; off >>= 1) sm += __shfl_xor(sm, off);
            float alpha = e / sm;
            alphaS[h * 64 + lane] = alpha;
            // per-wave LDS ops are in-order; waitcnt forces the write to commit
            __asm__ volatile("s_waitcnt lgkmcnt(0)" ::: "memory");
            float macc = 0.f;
            #pragma unroll
            for (int s4 = 0; s4 < 64; s4 += 4) {
                float4 av = *(const float4*)&alphaS[h * 64 + s4];
                macc = fmaf(av.x, hreg[s4 + 0], macc);
                macc = fmaf(av.y, hreg[s4 + 1], macc);
                macc = fmaf(av.z, hreg[s4 + 2], macc);
                macc = fmaf(av.w, hreg[s4 + 3], macc);
            }
            HS[d * 260 + h * 64 + lane] = macc + bv;   // msg + gat_bias
        }
    }
    __syncthreads();

    // Phase F: x = relu(LN(msg + x_old))
    {
        int mF = tid >> 2, q = tid & 3;
        size_t xrow = base + mF * 256 + q * 64;
        float sum = 0.f, sum2 = 0.f;
        #pragma unroll
        for (int j = 0; j < 64; j += 4) {
            float4 ms = *(const float4*)&HS[mF * 260 + q * 64 + j];
            float4 xo = *(const float4*)&xbuf[xrow + j];
            float v0 = ms.x + xo.x, v1 = ms.y + xo.y, v2 = ms.z + xo.z, v3 = ms.w + xo.w;
            sum += v0 + v1 + v2 + v3;
            sum2 += v0 * v0 + v1 * v1 + v2 * v2 + v3 * v3;
        }
        sum += __shfl_xor(sum, 1);  sum += __shfl_xor(sum, 2);
        sum2 += __shfl_xor(sum2, 1); sum2 += __shfl_xor(sum2, 2);
        float mu = sum * (1.f / 256.f);
        float var = sum2 * (1.f / 256.f) - mu * mu;
        float rstd = rsqrtf(var + 1e-5f);
        #pragma unroll
        for (int j = 0; j < 64; j += 4) {
            float4 ms = *(const float4*)&HS[mF * 260 + q * 64 + j];
            float4 xo = *(const float4*)&xbuf[xrow + j];
            float4 sc = *(const float4*)&lns[q * 64 + j];
            float4 bb = *(const float4*)&lnb[q * 64 + j];
            float4 o;
            o.x = fmaxf((ms.x + xo.x - mu) * rstd * sc.x + bb.x, 0.f);
            o.y = fmaxf((ms.y + xo.y - mu) * rstd * sc.y + bb.y, 0.f);
            o.z = fmaxf((ms.z + xo.z - mu) * rstd * sc.z + bb.z, 0.f);
            o.w = fmaxf((ms.w + xo.w - mu) * rstd * sc.w + bb.w, 0.f);
            *(float4*)&xbuf[xrow + j] = o;
        }
    }
}

// ---------------------------------------------------------------------------
// frame = masked mean over M; y = frame @ temp_W^T + temp_b + pos_emb[t]
__global__ __launch_bounds__(256) void k_frame_temp(const float* __restrict__ xbuf,
                                                    const float* __restrict__ mask,
                                                    const float* __restrict__ tW,
                                                    const float* __restrict__ tb,
                                                    const float* __restrict__ pe,
                                                    float* __restrict__ ybuf) {
    int bt = blockIdx.x;
    int t = bt & 31;
    size_t base = (size_t)bt * 64 * 256;
    __shared__ float frS[256];
    __shared__ float nvS;
    int tid = threadIdx.x;
    if (tid == 0) {
        float nv = 0.f;
        for (int m = 0; m < 64; m++) nv += (mask[bt * 64 + m] > 0.5f) ? 1.f : 0.f;
        nvS = fmaxf(nv, 1.f);
    }
    float fr = 0.f;
    for (int m = 0; m < 64; m++) {
        float vmv = mask[bt * 64 + m] > 0.5f ? 1.f : 0.f;
        fr += xbuf[base + m * 256 + tid] * vmv;
    }
    __syncthreads();
    frS[tid] = fr / nvS;
    __syncthreads();
    float acc = tb[tid] + pe[t * 256 + tid];
    const float* wrow = tW + (size_t)tid * 256;
    for (int g = 0; g < 256; g += 4) {
        float4 f = *(const float4*)&frS[g];
        float4 wv = *(const float4*)&wrow[g];
        acc += dot4(f, wv);
    }
    ybuf[bt * 256 + tid] = acc;
}

// ---------------------------------------------------------------------------
// z = LN1(y); qkv = z @ qkv_W^T + qkv_b   (768 outputs, 3 per thread)
__global__ __launch_bounds__(256) void k_ln_qkv(const float* __restrict__ ybuf,
                                                const float* __restrict__ ln_s,
                                                const float* __restrict__ ln_b,
                                                const float* __restrict__ qW,
                                                const float* __restrict__ qb,
                                                float* __restrict__ qkvbuf) {
    int bt = blockIdx.x, tid = threadIdx.x;
    __shared__ float zS[256];
    __shared__ float red[8];
    float yv = ybuf[bt * 256 + tid];
    float s = yv, s2 = yv * yv;
    block_reduce2(s, s2, red);
    float mu = s * (1.f / 256.f);
    float var = s2 * (1.f / 256.f) - mu * mu;
    float rstd = rsqrtf(var + 1e-5f);
    zS[tid] = (yv - mu) * rstd * ln_s[tid] + ln_b[tid];
    __syncthreads();
    for (int r = 0; r < 3; r++) {
        int j = r * 256 + tid;
        float acc = qb[j];
        const float* wrow = qW + (size_t)j * 256;
        for (int i = 0; i < 256; i += 4) {
            float4 z = *(const float4*)&zS[i];
            float4 wv = *(const float4*)&wrow[i];
            acc += dot4(z, wv);
        }
        qkvbuf[(size_t)bt * 768 + j] = acc;
    }
}

// ---------------------------------------------------------------------------
// Per (b, head) attention over T=32 tokens, hd=32.
__global__ __launch_bounds__(64) void k_attn(const float* __restrict__ qkvbuf,
                                             float* __restrict__ obuf) {
    int blk = blockIdx.x;          // b*8 + h
    int b = blk >> 3, h = blk & 7;
    int tid = threadIdx.x;
    __shared__ float Ks[32 * 32], Vs[32 * 32];
    for (int idx = tid; idx < 1024; idx += 64) {
        int tk = idx >> 5, c = idx & 31;
        size_t qbase = ((size_t)(b * 32 + tk)) * 768 + h * 32 + c;
        Ks[idx] = qkvbuf[qbase + 256];
        Vs[idx] = qkvbuf[qbase + 512];
    }
    __syncthreads();
    if (tid < 32) {
        int tq = tid;
        float qv[32];
        size_t qb0 = ((size_t)(b * 32 + tq)) * 768 + h * 32;
        #pragma unroll
        for (int c = 0; c < 32; c++) qv[c] = qkvbuf[qb0 + c];
        float scr[32];
        float mx = -1e30f;
        #pragma unroll
        for (int tk = 0; tk < 32; tk++) {
            float dd = 0.f;
            #pragma unroll
            for (int c = 0; c < 32; c++) dd = fmaf(qv[c], Ks[tk * 32 + c], dd);
            dd *= 0.17677669529663687f;   // 1/sqrt(32)
            scr[tk] = dd;
            mx = fmaxf(mx, dd);
        }
        float sm = 0.f;
        #pragma unroll
        for (int tk = 0; tk < 32; tk++) { scr[tk] = __expf(scr[tk] - mx); sm += scr[tk]; }
        float inv = 1.f / sm;
        float o[32];
        #pragma unroll
        for (int c = 0; c < 32; c++) o[c] = 0.f;
        #pragma unroll
        for (int tk = 0; tk < 32; tk++) {
            float a = scr[tk] * inv;
            #pragma unroll
            for (int c = 0; c < 32; c++) o[c] = fmaf(a, Vs[tk * 32 + c], o[c]);
        }
        size_t ob = ((size_t)(b * 32 + tq)) * 256 + h * 32;
        #pragma unroll
        for (int c = 0; c < 32; c++) obuf[ob + c] = o[c];
    }
}

// ---------------------------------------------------------------------------
// y += o @ attn_out_W^T + attn_out_b
__global__ __launch_bounds__(256) void k_attn_out(const float* __restrict__ obuf,
                                                  const float* __restrict__ W,
                                                  const float* __restrict__ bvec,
                                                  float* __restrict__ ybuf) {
    int bt = blockIdx.x, tid = threadIdx.x;
    __shared__ float oS[256];
    oS[tid] = obuf[bt * 256 + tid];
    __syncthreads();
    float acc = bvec[tid];
    const float* wrow = W + (size_t)tid * 256;
    for (int i = 0; i < 256; i += 4) {
        float4 o = *(const float4*)&oS[i];
        float4 wv = *(const float4*)&wrow[i];
        acc += dot4(o, wv);
    }
    ybuf[bt * 256 + tid] += acc;
}

// ---------------------------------------------------------------------------
// z = LN2(y); y += relu(z @ ff1^T + b1) @ ff2^T + b2
__global__ __launch_bounds__(256) void k_ff(float* __restrict__ ybuf,
                                            const float* __restrict__ ln_s,
                                            const float* __restrict__ ln_b,
                                            const float* __restrict__ W1,
                                            const float* __restrict__ b1,
                                            const float* __restrict__ W2,
                                            const float* __restrict__ b2) {
    int bt = blockIdx.x, tid = threadIdx.x;
    __shared__ float zS[256];
    __shared__ float fS[512];
    __shared__ float red[8];
    float yv = ybuf[bt * 256 + tid];
    float s = yv, s2 = yv * yv;
    block_reduce2(s, s2, red);
    float mu = s * (1.f / 256.f);
    float var = s2 * (1.f / 256.f) - mu * mu;
    float rstd = rsqrtf(var + 1e-5f);
    zS[tid] = (yv - mu) * rstd * ln_s[tid] + ln_b[tid];
    __syncthreads();
    for (int r = 0; r < 2; r++) {
        int j = r * 256 + tid;
        float acc = b1[j];
        const float* wrow = W1 + (size_t)j * 256;
        for (int i = 0; i < 256; i += 4) {
            float4 z = *(const float4*)&zS[i];
            float4 wv = *(const float4*)&wrow[i];
            acc += dot4(z, wv);
        }
        fS[j] = fmaxf(acc, 0.f);
    }
    __syncthreads();
    float acc = b2[tid];
    const float* wrow = W2 + (size_t)tid * 512;
    for (int j = 0; j < 512; j += 4) {
        float4 f = *(const float4*)&fS[j];
        float4 wv = *(const float4*)&wrow[j];
        acc += dot4(f, wv);
    }
    ybuf[bt * 256 + tid] = yv + acc;
}

// ---------------------------------------------------------------------------
// Attention pooling over T + output head + LN + relu. One block per b.
__global__ __launch_bounds__(256) void k_pool_out(const float* __restrict__ ybuf,
                                                  const float* __restrict__ pW,
                                                  const float* __restrict__ pb,
                                                  const float* __restrict__ oW,
                                                  const float* __restrict__ ob,
                                                  const float* __restrict__ lns,
                                                  const float* __restrict__ lnb,
                                                  float* __restrict__ dout) {
    int b = blockIdx.x, tid = threadIdx.x;
    __shared__ float redP[256];
    __shared__ float wS[32];
    __shared__ float pS[256];
    __shared__ float red[8];
    int tq = tid >> 3, part = tid & 7;
    float partial = 0.f;
    {
        const float* yrow = ybuf + ((size_t)(b * 32 + tq)) * 256 + part * 32;
        const float* pwp = pW + part * 32;
        #pragma unroll
        for (int j = 0; j < 32; j += 4) {
            float4 yv = *(const float4*)&yrow[j];
            float4 wv = *(const float4*)&pwp[j];
            partial += dot4(yv, wv);
        }
    }
    redP[tid] = partial;
    __syncthreads();
    if (tid < 32) {
        float s = pb[0];
        for (int p = 0; p < 8; p++) s += redP[tid * 8 + p];
        float mx = s;
        #pragma unroll
        for (int off = 16; off; off >>= 1) mx = fmaxf(mx, __shfl_xor(mx, off));
        float e = __expf(s - mx);
        float sm = e;
        #pragma unroll
        for (int off = 16; off; off >>= 1) sm += __shfl_xor(sm, off);
        wS[tid] = e / sm;
    }
    __syncthreads();
    float p = 0.f;
    for (int t = 0; t < 32; t++) p += ybuf[((size_t)(b * 32 + t)) * 256 + tid] * wS[t];
    pS[tid] = p;
    __syncthreads();
    float accs[2];
    for (int r = 0; r < 2; r++) {
        int j = r * 256 + tid;
        float acc = ob[j];
        const float* wrow = oW + (size_t)j * 256;
        for (int g = 0; g < 256; g += 4) {
            float4 pv = *(const float4*)&pS[g];
            float4 wv = *(const float4*)&wrow[g];
            acc += dot4(pv, wv);
        }
        accs[r] = acc;
    }
    float s = accs[0] + accs[1];
    float s2 = accs[0] * accs[0] + accs[1] * accs[1];
    block_reduce2(s, s2, red);
    float mu = s * (1.f / 512.f);
    float var = s2 * (1.f / 512.f) - mu * mu;
    float rstd = rsqrtf(var + 1e-5f);
    dout[b * 512 + tid]       = fmaxf((accs[0] - mu) * rstd * lns[tid] + lnb[tid], 0.f);
    dout[b * 512 + tid + 256] = fmaxf((accs[1] - mu) * rstd * lns[tid + 256] + lnb[tid + 256], 0.f);
}

// ---------------------------------------------------------------------------
extern "C" void kernel_launch(void* const* d_in, const int* in_sizes, int n_in,
                              void* d_out, int out_size, void* d_ws, size_t ws_size,
                              hipStream_t stream) {
    const float* drone_feats = (const float*)d_in[0];
    const float* boxes       = (const float*)d_in[1];
    const float* drone_mask  = (const float*)d_in[2];
    const float* in_proj_W   = (const float*)d_in[3];
    const float* in_proj_b   = (const float*)d_in[4];
    const float* gat_lin_W   = (const float*)d_in[5];
    const float* gat_edge_W  = (const float*)d_in[6];
    const float* gat_att_src = (const float*)d_in[7];
    const float* gat_att_dst = (const float*)d_in[8];
    const float* gat_att_edge= (const float*)d_in[9];
    const float* gat_bias    = (const float*)d_in[10];
    const float* gat_ln_s    = (const float*)d_in[11];
    const float* gat_ln_b    = (const float*)d_in[12];
    const float* temp_W      = (const float*)d_in[13];
    const float* temp_b      = (const float*)d_in[14];
    const float* pos_emb     = (const float*)d_in[15];
    const float* qkv_W       = (const float*)d_in[16];
    const float* qkv_b       = (const float*)d_in[17];
    const float* attn_out_W  = (const float*)d_in[18];
    const float* attn_out_b  = (const float*)d_in[19];
    const float* ln1_s       = (const float*)d_in[20];
    const float* ln1_b       = (const float*)d_in[21];
    const float* ln2_s       = (const float*)d_in[22];
    const float* ln2_b       = (const float*)d_in[23];
    const float* ff1_W       = (const float*)d_in[24];
    const float* ff1_b       = (const float*)d_in[25];
    const float* ff2_W       = (const float*)d_in[26];
    const float* ff2_b       = (const float*)d_in[27];
    const float* pool_W      = (const float*)d_in[28];
    const float* pool_b      = (const float*)d_in[29];
    const float* out_W       = (const float*)d_in[30];
    const float* out_b       = (const float*)d_in[31];
    const float* out_ln_s    = (const float*)d_in[32];
    const float* out_ln_b    = (const float*)d_in[33];
    float* out = (float*)d_out;

    // workspace layout (floats): geo 33.5M, xbuf 33.5M, WT 64K, y 512K, qkv 1.5M, o 512K
    float* ws = (float*)d_ws;
    float4* geo = (float4*)ws;
    size_t off = (size_t)BT * 64 * 64 * 4;
    float* xbuf   = ws + off; off += (size_t)BT * 64 * 256;
    float* WT     = ws + off; off += 65536;
    float* ybuf   = ws + off; off += (size_t)BT * 256;
    float* qkvbuf = ws + off; off += (size_t)BT * 768;
    float* obuf   = ws + off; off += (size_t)BT * 256;

    k_transpose256<<<dim3(256), dim3(256), 0, stream>>>(in_proj_W, WT);
    k_geo<<<dim3(BT), dim3(64), 0, stream>>>(boxes, drone_mask, geo);
    k_inproj<<<dim3(BT), dim3(256), 0, stream>>>(drone_feats, WT, in_proj_b, drone_mask, xbuf);
    for (int l = 0; l < 3; l++) {
        k_gat<<<dim3(BT), dim3(256), 0, stream>>>(xbuf, geo,
            gat_lin_W + (size_t)l * 65536, gat_edge_W + (size_t)l * 768,
            gat_att_src + (size_t)l * 256, gat_att_dst + (size_t)l * 256,
            gat_att_edge + (size_t)l * 256, gat_bias + (size_t)l * 256,
            gat_ln_s + (size_t)l * 256, gat_ln_b + (size_t)l * 256);
    }
    k_frame_temp<<<dim3(BT), dim3(256), 0, stream>>>(xbuf, drone_mask, temp_W, temp_b, pos_emb, ybuf);
    for (int l = 0; l < 2; l++) {
        k_ln_qkv<<<dim3(BT), dim3(256), 0, stream>>>(ybuf, ln1_s + l * 256, ln1_b + l * 256,
            qkv_W + (size_t)l * 768 * 256, qkv_b + l * 768, qkvbuf);
        k_attn<<<dim3(512), dim3(64), 0, stream>>>(qkvbuf, obuf);
        k_attn_out<<<dim3(BT), dim3(256), 0, stream>>>(obuf,
            attn_out_W + (size_t)l * 65536, attn_out_b + l * 256, ybuf);
        k_ff<<<dim3(BT), dim3(256), 0, stream>>>(ybuf, ln2_s + l * 256, ln2_b + l * 256,
            ff1_W + (size_t)l * 131072, ff1_b + l * 512,
            ff2_W + (size_t)l * 131072, ff2_b + l * 256);
    }
    k_pool_out<<<dim3(64), dim3(256), 0, stream>>>(ybuf, pool_W, pool_b, out_W, out_b,
                                                   out_ln_s, out_ln_b, out);
}

// Round 3
// 2517.472 us; speedup vs baseline: 1.2821x; 1.2821x over previous
//
#include <hip/hip_runtime.h>
#include <math.h>

#define BT 2048

typedef __attribute__((ext_vector_type(8))) short bf16x8;
typedef __attribute__((ext_vector_type(4))) float f32x4;

__device__ inline unsigned short f2bf(float f) {
    union { float f; unsigned u; } v; v.f = f;
    unsigned r = (v.u >> 16) & 1u;
    return (unsigned short)((v.u + 0x7FFFu + r) >> 16);
}
__device__ inline float bf2f(unsigned short s) {
    union { unsigned u; float f; } v; v.u = ((unsigned)s) << 16;
    return v.f;
}

__device__ inline float dot4(const float4 a, const float4 b) {
    return fmaf(a.x, b.x, fmaf(a.y, b.y, fmaf(a.z, b.z, a.w * b.w)));
}

__device__ inline void block_reduce2(float& a, float& b, float* red) {
    #pragma unroll
    for (int off = 32; off; off >>= 1) {
        a += __shfl_xor(a, off);
        b += __shfl_xor(b, off);
    }
    int wid = threadIdx.x >> 6;
    int lane = threadIdx.x & 63;
    if (lane == 0) { red[wid] = a; red[4 + wid] = b; }
    __syncthreads();
    a = red[0] + red[1] + red[2] + red[3];
    b = red[4] + red[5] + red[6] + red[7];
    __syncthreads();
}

// ---------------------------------------------------------------------------
// Pre-swizzle weights into MFMA B-fragment order, SPLIT bf16 hi/lo.
// frag-lane r = (ks*16+nt)*64+lane; dst[(mat*16384+r)*16 + j] = hi_j, +8+j = lo_j
// element: B^T[n = nt*16+(lane&15)][k = ks*32+(lane>>4)*8+j]
// mat 0: in_proj_W [out g][in i] -> tr;  mat 1..3: gat_lin_W[l] [g][k'] -> direct
__global__ __launch_bounds__(256) void k_prep(const float* __restrict__ inW,
                                              const float* __restrict__ gatW,
                                              unsigned short* __restrict__ dst) {
    int gid = blockIdx.x * 256 + threadIdx.x;   // 0..65535
    int mat = gid >> 14;
    int r   = gid & 16383;
    int ks  = r >> 10;
    int nt  = (r >> 6) & 15;
    int lane = r & 63;
    int ln15 = lane & 15, q = lane >> 4;
    int n  = nt * 16 + ln15;
    int k0 = ks * 32 + q * 8;
    const float* src; bool tr;
    if (mat == 0) { src = inW; tr = true; }
    else          { src = gatW + (size_t)(mat - 1) * 65536; tr = false; }
    unsigned short* d = dst + ((size_t)mat * 16384 + r) * 16;
    #pragma unroll
    for (int j = 0; j < 8; j++) {
        float v = tr ? src[n * 256 + k0 + j] : src[(size_t)(k0 + j) * 256 + n];
        unsigned short hi = f2bf(v);
        d[j]     = hi;
        d[8 + j] = f2bf(v - bf2f(hi));
    }
}

// ---------------------------------------------------------------------------
__global__ __launch_bounds__(64) void k_geo(const float* __restrict__ boxes,
                                            const float* __restrict__ mask,
                                            float4* __restrict__ geo) {
    int bt = blockIdx.x;
    __shared__ float px[64], py[64], vm[64];
    int m = threadIdx.x;
    const float* bx = boxes + (size_t)(bt * 64 + m) * 5;
    px[m] = bx[1];
    py[m] = bx[2];
    vm[m] = mask[bt * 64 + m];
    __syncthreads();
    int d = m;
    bool vd = vm[d] > 0.5f;
    float deg = 0.f, s0 = 0.f, s1 = 0.f, s2 = 0.f;
    for (int s = 0; s < 64; s++) {
        float rx = px[d] - px[s], ry = py[d] - py[s];
        float dist = sqrtf(fmaxf(rx * rx + ry * ry, 1e-12f));
        bool adj = vd && (vm[s] > 0.5f) && (dist < 0.3f) && (s != d);
        if (adj) { deg += 1.f; s0 += dist; s1 += rx; s2 += ry; }
    }
    float dg = fmaxf(deg, 1.f);
    float l0 = s0 / dg, l1 = s1 / dg, l2 = s2 / dg;
    float4* row = geo + (size_t)(bt * 64 + d) * 64;
    for (int s = 0; s < 64; s++) {
        float rx = px[d] - px[s], ry = py[d] - py[s];
        float dist = sqrtf(fmaxf(rx * rx + ry * ry, 1e-12f));
        bool adj = vd && (vm[s] > 0.5f) && (dist < 0.3f) && (s != d);
        float4 v;
        if (adj)            v = make_float4(dist, rx, ry, 1.f);
        else if (s == d)    v = make_float4(l0, l1, l2, vd ? 1.f : 0.f);
        else                v = make_float4(0.f, 0.f, 0.f, 0.f);
        row[s] = v;
    }
}

// split a float8 (two float4) into hi/lo bf16x8 fragments
__device__ inline void split8(const float4 a0, const float4 a1, bf16x8& hi, bf16x8& lo) {
    union { bf16x8 v; unsigned short u[8]; } H, L;
    float f[8] = {a0.x, a0.y, a0.z, a0.w, a1.x, a1.y, a1.z, a1.w};
    #pragma unroll
    for (int j = 0; j < 8; j++) {
        H.u[j] = f2bf(f[j]);
        L.u[j] = f2bf(f[j] - bf2f(H.u[j]));
    }
    hi = H.v; lo = L.v;
}

// ---------------------------------------------------------------------------
// in_proj via split MFMA: x[bt] = (feats[bt] @ W^T + b) * mask
__global__ __launch_bounds__(256, 3) void k_inproj(const float* __restrict__ feats,
                                                   const unsigned short* __restrict__ Bsw,
                                                   const float* __restrict__ bias,
                                                   const float* __restrict__ mask,
                                                   float* __restrict__ xbuf) {
    int bt = blockIdx.x;
    size_t base = (size_t)bt * 64 * 256;
    int lane = threadIdx.x & 63, w = threadIdx.x >> 6;
    int ln15 = lane & 15, q = lane >> 4;
    int m0 = w * 16;
    f32x4 acc[16];
    #pragma unroll
    for (int nt = 0; nt < 16; nt++) acc[nt] = (f32x4){0.f, 0.f, 0.f, 0.f};
    const float* arow = feats + base + (size_t)(m0 + ln15) * 256 + q * 8;
    for (int ks = 0; ks < 8; ks++) {
        float4 a0 = *(const float4*)&arow[ks * 32];
        float4 a1 = *(const float4*)&arow[ks * 32 + 4];
        bf16x8 ahi, alo;
        split8(a0, a1, ahi, alo);
        #pragma unroll
        for (int nt = 0; nt < 16; nt++) {
            const unsigned short* fb = &Bsw[((size_t)(ks * 16 + nt) * 64 + lane) * 16];
            bf16x8 bhi = *(const bf16x8*)&fb[0];
            bf16x8 blo = *(const bf16x8*)&fb[8];
            acc[nt] = __builtin_amdgcn_mfma_f32_16x16x32_bf16(ahi, bhi, acc[nt], 0, 0, 0);
            acc[nt] = __builtin_amdgcn_mfma_f32_16x16x32_bf16(alo, bhi, acc[nt], 0, 0, 0);
            acc[nt] = __builtin_amdgcn_mfma_f32_16x16x32_bf16(ahi, blo, acc[nt], 0, 0, 0);
        }
    }
    float mk[4];
    #pragma unroll
    for (int r = 0; r < 4; r++) mk[r] = mask[bt * 64 + m0 + q * 4 + r] > 0.5f ? 1.f : 0.f;
    #pragma unroll
    for (int nt = 0; nt < 16; nt++) {
        float bv = bias[nt * 16 + ln15];
        #pragma unroll
        for (int r = 0; r < 4; r++) {
            xbuf[base + (size_t)(m0 + q * 4 + r) * 256 + nt * 16 + ln15] = (acc[nt][r] + bv) * mk[r];
        }
    }
}

// ---------------------------------------------------------------------------
// Fused GAT layer. One fp32 LDS tile 64x260, reused: x -> h -> msg.
//  A: x fp32 global -> LDS.  B: h = x@W via split MFMA (wave owns rows 16w..16w+15,
//     reads/writes only its own rows -> no barrier between B and C).
//  D: a_src/a_dst/w_e (fp32).  E: per-head softmax + message, 4 dests/iter.
//  F: x = relu(LN(msg + x_old)).
__global__ __launch_bounds__(256, 2) void k_gat(float* __restrict__ xbuf,
                                                const float4* __restrict__ geo,
                                                const unsigned short* __restrict__ Bsw,
                                                const float* __restrict__ edgeW,
                                                const float* __restrict__ attS,
                                                const float* __restrict__ attD,
                                                const float* __restrict__ attE,
                                                const float* __restrict__ bias,
                                                const float* __restrict__ lns,
                                                const float* __restrict__ lnb) {
    int bt = blockIdx.x;
    size_t base = (size_t)bt * 64 * 256;
    __shared__ float XS[64 * 260];               // fp32 tile: x, then h, then msg
    __shared__ float asrcS[256], adstS[256], wES[12], alphaS[16 * 64];
    int tid = threadIdx.x, lane = tid & 63, w = tid >> 6;
    int ln15 = lane & 15, q = lane >> 4;

    // Phase A: x -> LDS (fp32)
    for (int idx = tid; idx < 2048; idx += 256) {
        int m = idx >> 5, c8 = (idx & 31) * 8;
        float4 v0 = *(const float4*)&xbuf[base + m * 256 + c8];
        float4 v1 = *(const float4*)&xbuf[base + m * 256 + c8 + 4];
        *(float4*)&XS[m * 260 + c8] = v0;
        *(float4*)&XS[m * 260 + c8 + 4] = v1;
    }
    __syncthreads();

    // Phase B: split MFMA. Wave w computes h rows [16w, 16w+16) x 256 cols.
    int m0 = w * 16;
    f32x4 acc[16];
    #pragma unroll
    for (int nt = 0; nt < 16; nt++) acc[nt] = (f32x4){0.f, 0.f, 0.f, 0.f};
    const float* arow = &XS[(m0 + ln15) * 260 + q * 8];
    for (int ks = 0; ks < 8; ks++) {
        float4 a0 = *(const float4*)&arow[ks * 32];
        float4 a1 = *(const float4*)&arow[ks * 32 + 4];
        bf16x8 ahi, alo;
        split8(a0, a1, ahi, alo);
        #pragma unroll
        for (int nt = 0; nt < 16; nt++) {
            const unsigned short* fb = &Bsw[((size_t)(ks * 16 + nt) * 64 + lane) * 16];
            bf16x8 bhi = *(const bf16x8*)&fb[0];
            bf16x8 blo = *(const bf16x8*)&fb[8];
            acc[nt] = __builtin_amdgcn_mfma_f32_16x16x32_bf16(ahi, bhi, acc[nt], 0, 0, 0);
            acc[nt] = __builtin_amdgcn_mfma_f32_16x16x32_bf16(alo, bhi, acc[nt], 0, 0, 0);
            acc[nt] = __builtin_amdgcn_mfma_f32_16x16x32_bf16(ahi, blo, acc[nt], 0, 0, 0);
        }
    }
    // Phase C: write h fp32 (own rows only — no barrier needed vs Phase B)
    #pragma unroll
    for (int nt = 0; nt < 16; nt++) {
        #pragma unroll
        for (int r = 0; r < 4; r++) {
            XS[(size_t)(m0 + q * 4 + r) * 260 + nt * 16 + ln15] = acc[nt][r];
        }
    }
    __syncthreads();

    // Phase D: a_src/a_dst per (m=lane, head=w); w_e
    {
        int hh = w, mD = lane;
        float s1 = 0.f, s2 = 0.f;
        const float* hr = &XS[mD * 260 + hh * 64];
        const float* pS = attS + hh * 64;
        const float* pD = attD + hh * 64;
        #pragma unroll
        for (int c = 0; c < 64; c += 4) {
            float4 hv = *(const float4*)&hr[c];
            float4 a1 = *(const float4*)&pS[c];
            float4 a2 = *(const float4*)&pD[c];
            s1 += dot4(hv, a1);
            s2 += dot4(hv, a2);
        }
        asrcS[hh * 64 + mD] = s1;
        adstS[hh * 64 + mD] = s2;
        if (tid < 12) {
            int e = tid >> 2, h2 = tid & 3;
            float sm = 0.f;
            for (int c = 0; c < 64; c++)
                sm += edgeW[e * 256 + h2 * 64 + c] * attE[h2 * 64 + c];
            wES[e * 4 + h2] = sm;
        }
    }
    __syncthreads();

    // Phase E: wave w = head h; lane = source s; 4 dests per iteration.
    // Wave h only touches columns [h*64, h*64+64) of XS — no cross-wave races.
    {
        int h = w;
        float hreg[64];
        #pragma unroll
        for (int ss = 0; ss < 64; ss++) hreg[ss] = XS[ss * 260 + h * 64 + lane];
        float we0 = wES[0 * 4 + h], we1 = wES[1 * 4 + h], we2 = wES[2 * 4 + h];
        float a_s = asrcS[h * 64 + lane];
        float bv = bias[h * 64 + lane];
        const float4* grow = geo + (size_t)bt * 4096;
        float4 g[4], gn[4];
        #pragma unroll
        for (int i = 0; i < 4; i++) g[i] = grow[i * 64 + lane];
        for (int dg = 0; dg < 64; dg += 4) {
            if (dg < 60) {
                #pragma unroll
                for (int i = 0; i < 4; i++) gn[i] = grow[(dg + 4 + i) * 64 + lane];
            }
            float lg[4], mx[4], ee[4], sm[4];
            #pragma unroll
            for (int i = 0; i < 4; i++) {
                float l = a_s + adstS[h * 64 + dg + i]
                        + g[i].x * we0 + g[i].y * we1 + g[i].z * we2;
                l = l >= 0.f ? l : 0.2f * l;
                lg[i] = g[i].w > 0.5f ? l : -1e9f;
                mx[i] = lg[i];
            }
            #pragma unroll
            for (int off = 32; off; off >>= 1) {
                #pragma unroll
                for (int i = 0; i < 4; i++) mx[i] = fmaxf(mx[i], __shfl_xor(mx[i], off));
            }
            #pragma unroll
            for (int i = 0; i < 4; i++) { ee[i] = __expf(lg[i] - mx[i]); sm[i] = ee[i]; }
            #pragma unroll
            for (int off = 32; off; off >>= 1) {
                #pragma unroll
                for (int i = 0; i < 4; i++) sm[i] += __shfl_xor(sm[i], off);
            }
            #pragma unroll
            for (int i = 0; i < 4; i++) alphaS[(h * 4 + i) * 64 + lane] = ee[i] / sm[i];
            // per-wave LDS is in-order; drain writes before broadcast reads
            __asm__ volatile("s_waitcnt lgkmcnt(0)" ::: "memory");
            float mc[4] = {0.f, 0.f, 0.f, 0.f};
            #pragma unroll
            for (int s4 = 0; s4 < 64; s4 += 4) {
                #pragma unroll
                for (int i = 0; i < 4; i++) {
                    float4 av = *(const float4*)&alphaS[(h * 4 + i) * 64 + s4];
                    mc[i] = fmaf(av.x, hreg[s4 + 0],
                            fmaf(av.y, hreg[s4 + 1],
                            fmaf(av.z, hreg[s4 + 2],
                            fmaf(av.w, hreg[s4 + 3], mc[i]))));
                }
            }
            #pragma unroll
            for (int i = 0; i < 4; i++)
                XS[(size_t)(dg + i) * 260 + h * 64 + lane] = mc[i] + bv;
            #pragma unroll
            for (int i = 0; i < 4; i++) g[i] = gn[i];
        }
    }
    __syncthreads();

    // Phase F: x = relu(LN(msg + x_old))
    {
        int mF = tid >> 2, qF = tid & 3;
        size_t xrow = base + (size_t)mF * 256 + qF * 64;
        const float* mrow = &XS[mF * 260 + qF * 64];
        float sum = 0.f, sum2 = 0.f;
        #pragma unroll
        for (int j = 0; j < 64; j += 4) {
            float4 ms = *(const float4*)&mrow[j];
            float4 xo = *(const float4*)&xbuf[xrow + j];
            float v0 = ms.x + xo.x, v1 = ms.y + xo.y, v2 = ms.z + xo.z, v3 = ms.w + xo.w;
            sum  += v0 + v1 + v2 + v3;
            sum2 += v0*v0 + v1*v1 + v2*v2 + v3*v3;
        }
        sum  += __shfl_xor(sum, 1);  sum  += __shfl_xor(sum, 2);
        sum2 += __shfl_xor(sum2, 1); sum2 += __shfl_xor(sum2, 2);
        float mu = sum * (1.f / 256.f);
        float var = sum2 * (1.f / 256.f) - mu * mu;
        float rstd = rsqrtf(var + 1e-5f);
        #pragma unroll
        for (int j = 0; j < 64; j += 4) {
            float4 ms = *(const float4*)&mrow[j];
            float4 xo = *(const float4*)&xbuf[xrow + j];
            float4 sc = *(const float4*)&lns[qF * 64 + j];
            float4 bb = *(const float4*)&lnb[qF * 64 + j];
            float4 o;
            o.x = fmaxf((ms.x + xo.x - mu) * rstd * sc.x + bb.x, 0.f);
            o.y = fmaxf((ms.y + xo.y - mu) * rstd * sc.y + bb.y, 0.f);
            o.z = fmaxf((ms.z + xo.z - mu) * rstd * sc.z + bb.z, 0.f);
            o.w = fmaxf((ms.w + xo.w - mu) * rstd * sc.w + bb.w, 0.f);
            *(float4*)&xbuf[xrow + j] = o;
        }
    }
}

// ---------------------------------------------------------------------------
__global__ __launch_bounds__(256) void k_frame_temp(const float* __restrict__ xbuf,
                                                    const float* __restrict__ mask,
                                                    const float* __restrict__ tW,
                                                    const float* __restrict__ tb,
                                                    const float* __restrict__ pe,
                                                    float* __restrict__ ybuf) {
    int bt = blockIdx.x;
    int t = bt & 31;
    size_t base = (size_t)bt * 64 * 256;
    __shared__ float frS[256];
    __shared__ float nvS;
    int tid = threadIdx.x;
    if (tid == 0) {
        float nv = 0.f;
        for (int m = 0; m < 64; m++) nv += (mask[bt * 64 + m] > 0.5f) ? 1.f : 0.f;
        nvS = fmaxf(nv, 1.f);
    }
    float fr = 0.f;
    for (int m = 0; m < 64; m++) {
        float vmv = mask[bt * 64 + m] > 0.5f ? 1.f : 0.f;
        fr += xbuf[base + m * 256 + tid] * vmv;
    }
    __syncthreads();
    frS[tid] = fr / nvS;
    __syncthreads();
    float acc = tb[tid] + pe[t * 256 + tid];
    const float* wrow = tW + (size_t)tid * 256;
    for (int g = 0; g < 256; g += 4) {
        float4 f = *(const float4*)&frS[g];
        float4 wv = *(const float4*)&wrow[g];
        acc += dot4(f, wv);
    }
    ybuf[bt * 256 + tid] = acc;
}

// ---------------------------------------------------------------------------
__global__ __launch_bounds__(256) void k_ln_qkv(const float* __restrict__ ybuf,
                                                const float* __restrict__ ln_s,
                                                const float* __restrict__ ln_b,
                                                const float* __restrict__ qW,
                                                const float* __restrict__ qb,
                                                float* __restrict__ qkvbuf) {
    int bt = blockIdx.x, tid = threadIdx.x;
    __shared__ float zS[256];
    __shared__ float red[8];
    float yv = ybuf[bt * 256 + tid];
    float s = yv, s2 = yv * yv;
    block_reduce2(s, s2, red);
    float mu = s * (1.f / 256.f);
    float var = s2 * (1.f / 256.f) - mu * mu;
    float rstd = rsqrtf(var + 1e-5f);
    zS[tid] = (yv - mu) * rstd * ln_s[tid] + ln_b[tid];
    __syncthreads();
    for (int r = 0; r < 3; r++) {
        int j = r * 256 + tid;
        float acc = qb[j];
        const float* wrow = qW + (size_t)j * 256;
        for (int i = 0; i < 256; i += 4) {
            float4 z = *(const float4*)&zS[i];
            float4 wv = *(const float4*)&wrow[i];
            acc += dot4(z, wv);
        }
        qkvbuf[(size_t)bt * 768 + j] = acc;
    }
}

// ---------------------------------------------------------------------------
__global__ __launch_bounds__(64) void k_attn(const float* __restrict__ qkvbuf,
                                             float* __restrict__ obuf) {
    int blk = blockIdx.x;
    int b = blk >> 3, h = blk & 7;
    int tid = threadIdx.x;
    __shared__ float Ks[32 * 32], Vs[32 * 32];
    for (int idx = tid; idx < 1024; idx += 64) {
        int tk = idx >> 5, c = idx & 31;
        size_t qbase = ((size_t)(b * 32 + tk)) * 768 + h * 32 + c;
        Ks[idx] = qkvbuf[qbase + 256];
        Vs[idx] = qkvbuf[qbase + 512];
    }
    __syncthreads();
    if (tid < 32) {
        int tq = tid;
        float qv[32];
        size_t qb0 = ((size_t)(b * 32 + tq)) * 768 + h * 32;
        #pragma unroll
        for (int c = 0; c < 32; c++) qv[c] = qkvbuf[qb0 + c];
        float scr[32];
        float mx = -1e30f;
        #pragma unroll
        for (int tk = 0; tk < 32; tk++) {
            float dd = 0.f;
            #pragma unroll
            for (int c = 0; c < 32; c++) dd = fmaf(qv[c], Ks[tk * 32 + c], dd);
            dd *= 0.17677669529663687f;
            scr[tk] = dd;
            mx = fmaxf(mx, dd);
        }
        float sm = 0.f;
        #pragma unroll
        for (int tk = 0; tk < 32; tk++) { scr[tk] = __expf(scr[tk] - mx); sm += scr[tk]; }
        float inv = 1.f / sm;
        float o[32];
        #pragma unroll
        for (int c = 0; c < 32; c++) o[c] = 0.f;
        #pragma unroll
        for (int tk = 0; tk < 32; tk++) {
            float a = scr[tk] * inv;
            #pragma unroll
            for (int c = 0; c < 32; c++) o[c] = fmaf(a, Vs[tk * 32 + c], o[c]);
        }
        size_t ob = ((size_t)(b * 32 + tq)) * 256 + h * 32;
        #pragma unroll
        for (int c = 0; c < 32; c++) obuf[ob + c] = o[c];
    }
}

// ---------------------------------------------------------------------------
__global__ __launch_bounds__(256) void k_attn_out(const float* __restrict__ obuf,
                                                  const float* __restrict__ W,
                                                  const float* __restrict__ bvec,
                                                  float* __restrict__ ybuf) {
    int bt = blockIdx.x, tid = threadIdx.x;
    __shared__ float oS[256];
    oS[tid] = obuf[bt * 256 + tid];
    __syncthreads();
    float acc = bvec[tid];
    const float* wrow = W + (size_t)tid * 256;
    for (int i = 0; i < 256; i += 4) {
        float4 o = *(const float4*)&oS[i];
        float4 wv = *(const float4*)&wrow[i];
        acc += dot4(o, wv);
    }
    ybuf[bt * 256 + tid] += acc;
}

// ---------------------------------------------------------------------------
__global__ __launch_bounds__(256) void k_ff(float* __restrict__ ybuf,
                                            const float* __restrict__ ln_s,
                                            const float* __restrict__ ln_b,
                                            const float* __restrict__ W1,
                                            const float* __restrict__ b1,
                                            const float* __restrict__ W2,
                                            const float* __restrict__ b2) {
    int bt = blockIdx.x, tid = threadIdx.x;
    __shared__ float zS[256];
    __shared__ float fS[512];
    __shared__ float red[8];
    float yv = ybuf[bt * 256 + tid];
    float s = yv, s2 = yv * yv;
    block_reduce2(s, s2, red);
    float mu = s * (1.f / 256.f);
    float var = s2 * (1.f / 256.f) - mu * mu;
    float rstd = rsqrtf(var + 1e-5f);
    zS[tid] = (yv - mu) * rstd * ln_s[tid] + ln_b[tid];
    __syncthreads();
    for (int r = 0; r < 2; r++) {
        int j = r * 256 + tid;
        float acc = b1[j];
        const float* wrow = W1 + (size_t)j * 256;
        for (int i = 0; i < 256; i += 4) {
            float4 z = *(const float4*)&zS[i];
            float4 wv = *(const float4*)&wrow[i];
            acc += dot4(z, wv);
        }
        fS[j] = fmaxf(acc, 0.f);
    }
    __syncthreads();
    float acc = b2[tid];
    const float* wrow = W2 + (size_t)tid * 512;
    for (int j = 0; j < 512; j += 4) {
        float4 f = *(const float4*)&fS[j];
        float4 wv = *(const float4*)&wrow[j];
        acc += dot4(f, wv);
    }
    ybuf[bt * 256 + tid] = yv + acc;
}

// ---------------------------------------------------------------------------
__global__ __launch_bounds__(256) void k_pool_out(const float* __restrict__ ybuf,
                                                  const float* __restrict__ pW,
                                                  const float* __restrict__ pb,
                                                  const float* __restrict__ oW,
                                                  const float* __restrict__ ob,
                                                  const float* __restrict__ lns,
                                                  const float* __restrict__ lnb,
                                                  float* __restrict__ dout) {
    int b = blockIdx.x, tid = threadIdx.x;
    __shared__ float redP[256];
    __shared__ float wS[32];
    __shared__ float pS[256];
    __shared__ float red[8];
    int tq = tid >> 3, part = tid & 7;
    float partial = 0.f;
    {
        const float* yrow = ybuf + ((size_t)(b * 32 + tq)) * 256 + part * 32;
        const float* pwp = pW + part * 32;
        #pragma unroll
        for (int j = 0; j < 32; j += 4) {
            float4 yv = *(const float4*)&yrow[j];
            float4 wv = *(const float4*)&pwp[j];
            partial += dot4(yv, wv);
        }
    }
    redP[tid] = partial;
    __syncthreads();
    if (tid < 32) {
        float s = pb[0];
        for (int p = 0; p < 8; p++) s += redP[tid * 8 + p];
        float mx = s;
        #pragma unroll
        for (int off = 16; off; off >>= 1) mx = fmaxf(mx, __shfl_xor(mx, off));
        float e = __expf(s - mx);
        float sm = e;
        #pragma unroll
        for (int off = 16; off; off >>= 1) sm += __shfl_xor(sm, off);
        wS[tid] = e / sm;
    }
    __syncthreads();
    float p = 0.f;
    for (int t = 0; t < 32; t++) p += ybuf[((size_t)(b * 32 + t)) * 256 + tid] * wS[t];
    pS[tid] = p;
    __syncthreads();
    float accs[2];
    for (int r = 0; r < 2; r++) {
        int j = r * 256 + tid;
        float acc = ob[j];
        const float* wrow = oW + (size_t)j * 256;
        for (int g = 0; g < 256; g += 4) {
            float4 pv = *(const float4*)&pS[g];
            float4 wv = *(const float4*)&wrow[g];
            acc += dot4(pv, wv);
        }
        accs[r] = acc;
    }
    float s = accs[0] + accs[1];
    float s2 = accs[0] * accs[0] + accs[1] * accs[1];
    block_reduce2(s, s2, red);
    float mu = s * (1.f / 512.f);
    float var = s2 * (1.f / 512.f) - mu * mu;
    float rstd = rsqrtf(var + 1e-5f);
    dout[b * 512 + tid]       = fmaxf((accs[0] - mu) * rstd * lns[tid] + lnb[tid], 0.f);
    dout[b * 512 + tid + 256] = fmaxf((accs[1] - mu) * rstd * lns[tid + 256] + lnb[tid + 256], 0.f);
}

// ---------------------------------------------------------------------------
extern "C" void kernel_launch(void* const* d_in, const int* in_sizes, int n_in,
                              void* d_out, int out_size, void* d_ws, size_t ws_size,
                              hipStream_t stream) {
    const float* drone_feats = (const float*)d_in[0];
    const float* boxes       = (const float*)d_in[1];
    const float* drone_mask  = (const float*)d_in[2];
    const float* in_proj_W   = (const float*)d_in[3];
    const float* in_proj_b   = (const float*)d_in[4];
    const float* gat_lin_W   = (const float*)d_in[5];
    const float* gat_edge_W  = (const float*)d_in[6];
    const float* gat_att_src = (const float*)d_in[7];
    const float* gat_att_dst = (const float*)d_in[8];
    const float* gat_att_edge= (const float*)d_in[9];
    const float* gat_bias    = (const float*)d_in[10];
    const float* gat_ln_s    = (const float*)d_in[11];
    const float* gat_ln_b    = (const float*)d_in[12];
    const float* temp_W      = (const float*)d_in[13];
    const float* temp_b      = (const float*)d_in[14];
    const float* pos_emb     = (const float*)d_in[15];
    const float* qkv_W       = (const float*)d_in[16];
    const float* qkv_b       = (const float*)d_in[17];
    const float* attn_out_W  = (const float*)d_in[18];
    const float* attn_out_b  = (const float*)d_in[19];
    const float* ln1_s       = (const float*)d_in[20];
    const float* ln1_b       = (const float*)d_in[21];
    const float* ln2_s       = (const float*)d_in[22];
    const float* ln2_b       = (const float*)d_in[23];
    const float* ff1_W       = (const float*)d_in[24];
    const float* ff1_b       = (const float*)d_in[25];
    const float* ff2_W       = (const float*)d_in[26];
    const float* ff2_b       = (const float*)d_in[27];
    const float* pool_W      = (const float*)d_in[28];
    const float* pool_b      = (const float*)d_in[29];
    const float* out_W       = (const float*)d_in[30];
    const float* out_b       = (const float*)d_in[31];
    const float* out_ln_s    = (const float*)d_in[32];
    const float* out_ln_b    = (const float*)d_in[33];
    float* out = (float*)d_out;

    float* ws = (float*)d_ws;
    float4* geo = (float4*)ws;
    size_t off = (size_t)BT * 64 * 64 * 4;           // geo floats
    float* xbuf   = ws + off; off += (size_t)BT * 64 * 256;
    unsigned short* Bsw = (unsigned short*)(ws + off); off += 4 * 16384 * 16 / 2;  // hi/lo bf16
    float* ybuf   = ws + off; off += (size_t)BT * 256;
    float* qkvbuf = ws + off; off += (size_t)BT * 768;
    float* obuf   = ws + off; off += (size_t)BT * 256;

    k_prep<<<dim3(256), dim3(256), 0, stream>>>(in_proj_W, gat_lin_W, Bsw);
    k_geo<<<dim3(BT), dim3(64), 0, stream>>>(boxes, drone_mask, geo);
    k_inproj<<<dim3(BT), dim3(256), 0, stream>>>(drone_feats, Bsw, in_proj_b, drone_mask, xbuf);
    for (int l = 0; l < 3; l++) {
        k_gat<<<dim3(BT), dim3(256), 0, stream>>>(xbuf, geo,
            Bsw + (size_t)(1 + l) * 16384 * 16, gat_edge_W + (size_t)l * 768,
            gat_att_src + (size_t)l * 256, gat_att_dst + (size_t)l * 256,
            gat_att_edge + (size_t)l * 256, gat_bias + (size_t)l * 256,
            gat_ln_s + (size_t)l * 256, gat_ln_b + (size_t)l * 256);
    }
    k_frame_temp<<<dim3(BT), dim3(256), 0, stream>>>(xbuf, drone_mask, temp_W, temp_b, pos_emb, ybuf);
    for (int l = 0; l < 2; l++) {
        k_ln_qkv<<<dim3(BT), dim3(256), 0, stream>>>(ybuf, ln1_s + l * 256, ln1_b + l * 256,
            qkv_W + (size_t)l * 768 * 256, qkv_b + l * 768, qkvbuf);
        k_attn<<<dim3(512), dim3(64), 0, stream>>>(qkvbuf, obuf);
        k_attn_out<<<dim3(BT), dim3(256), 0, stream>>>(obuf,
            attn_out_W + (size_t)l * 65536, attn_out_b + l * 256, ybuf);
        k_ff<<<dim3(BT), dim3(256), 0, stream>>>(ybuf, ln2_s + l * 256, ln2_b + l * 256,
            ff1_W + (size_t)l * 131072, ff1_b + l * 512,
            ff2_W + (size_t)l * 131072, ff2_b + l * 256);
    }
    k_pool_out<<<dim3(64), dim3(256), 0, stream>>>(ybuf, pool_W, pool_b, out_W, out_b,
                                                   out_ln_s, out_ln_b, out);
}

// Round 4
// 2387.888 us; speedup vs baseline: 1.3516x; 1.0543x over previous
//
#include <hip/hip_runtime.h>
#include <math.h>

#define BT 2048

typedef __attribute__((ext_vector_type(8))) short bf16x8;
typedef __attribute__((ext_vector_type(4))) float f32x4;

__device__ inline unsigned short f2bf(float f) {
    union { float f; unsigned u; } v; v.f = f;
    unsigned r = (v.u >> 16) & 1u;
    return (unsigned short)((v.u + 0x7FFFu + r) >> 16);
}
__device__ inline float bf2f(unsigned short s) {
    union { unsigned u; float f; } v; v.u = ((unsigned)s) << 16;
    return v.f;
}

__device__ inline float dot4(const float4 a, const float4 b) {
    return fmaf(a.x, b.x, fmaf(a.y, b.y, fmaf(a.z, b.z, a.w * b.w)));
}

__device__ inline void block_reduce2(float& a, float& b, float* red) {
    #pragma unroll
    for (int off = 32; off; off >>= 1) {
        a += __shfl_xor(a, off);
        b += __shfl_xor(b, off);
    }
    int wid = threadIdx.x >> 6;
    int lane = threadIdx.x & 63;
    if (lane == 0) { red[wid] = a; red[4 + wid] = b; }
    __syncthreads();
    a = red[0] + red[1] + red[2] + red[3];
    b = red[4] + red[5] + red[6] + red[7];
    __syncthreads();
}

// ---------------------------------------------------------------------------
// Pre-swizzle weights into MFMA B-fragment order, SPLIT bf16 hi/lo.
__global__ __launch_bounds__(256) void k_prep(const float* __restrict__ inW,
                                              const float* __restrict__ gatW,
                                              unsigned short* __restrict__ dst) {
    int gid = blockIdx.x * 256 + threadIdx.x;   // 0..65535
    int mat = gid >> 14;
    int r   = gid & 16383;
    int ks  = r >> 10;
    int nt  = (r >> 6) & 15;
    int lane = r & 63;
    int ln15 = lane & 15, q = lane >> 4;
    int n  = nt * 16 + ln15;
    int k0 = ks * 32 + q * 8;
    const float* src; bool tr;
    if (mat == 0) { src = inW; tr = true; }
    else          { src = gatW + (size_t)(mat - 1) * 65536; tr = false; }
    unsigned short* d = dst + ((size_t)mat * 16384 + r) * 16;
    #pragma unroll
    for (int j = 0; j < 8; j++) {
        float v = tr ? src[n * 256 + k0 + j] : src[(size_t)(k0 + j) * 256 + n];
        unsigned short hi = f2bf(v);
        d[j]     = hi;
        d[8 + j] = f2bf(v - bf2f(hi));
    }
}

// split a float8 (two float4) into hi/lo bf16x8 fragments
__device__ inline void split8(const float4 a0, const float4 a1, bf16x8& hi, bf16x8& lo) {
    union { bf16x8 v; unsigned short u[8]; } H, L;
    float f[8] = {a0.x, a0.y, a0.z, a0.w, a1.x, a1.y, a1.z, a1.w};
    #pragma unroll
    for (int j = 0; j < 8; j++) {
        H.u[j] = f2bf(f[j]);
        L.u[j] = f2bf(f[j] - bf2f(H.u[j]));
    }
    hi = H.v; lo = L.v;
}

// ---------------------------------------------------------------------------
// in_proj via split MFMA: x[bt] = (feats[bt] @ W^T + b) * mask
__global__ __launch_bounds__(256, 3) void k_inproj(const float* __restrict__ feats,
                                                   const unsigned short* __restrict__ Bsw,
                                                   const float* __restrict__ bias,
                                                   const float* __restrict__ mask,
                                                   float* __restrict__ xbuf) {
    int bt = blockIdx.x;
    size_t base = (size_t)bt * 64 * 256;
    int lane = threadIdx.x & 63, w = threadIdx.x >> 6;
    int ln15 = lane & 15, q = lane >> 4;
    int m0 = w * 16;
    f32x4 acc[16];
    #pragma unroll
    for (int nt = 0; nt < 16; nt++) acc[nt] = (f32x4){0.f, 0.f, 0.f, 0.f};
    const float* arow = feats + base + (size_t)(m0 + ln15) * 256 + q * 8;
    for (int ks = 0; ks < 8; ks++) {
        float4 a0 = *(const float4*)&arow[ks * 32];
        float4 a1 = *(const float4*)&arow[ks * 32 + 4];
        bf16x8 ahi, alo;
        split8(a0, a1, ahi, alo);
        #pragma unroll
        for (int nt = 0; nt < 16; nt++) {
            const unsigned short* fb = &Bsw[((size_t)(ks * 16 + nt) * 64 + lane) * 16];
            bf16x8 bhi = *(const bf16x8*)&fb[0];
            bf16x8 blo = *(const bf16x8*)&fb[8];
            acc[nt] = __builtin_amdgcn_mfma_f32_16x16x32_bf16(ahi, bhi, acc[nt], 0, 0, 0);
            acc[nt] = __builtin_amdgcn_mfma_f32_16x16x32_bf16(alo, bhi, acc[nt], 0, 0, 0);
            acc[nt] = __builtin_amdgcn_mfma_f32_16x16x32_bf16(ahi, blo, acc[nt], 0, 0, 0);
        }
    }
    float mk[4];
    #pragma unroll
    for (int r = 0; r < 4; r++) mk[r] = mask[bt * 64 + m0 + q * 4 + r] > 0.5f ? 1.f : 0.f;
    #pragma unroll
    for (int nt = 0; nt < 16; nt++) {
        float bv = bias[nt * 16 + ln15];
        #pragma unroll
        for (int r = 0; r < 4; r++) {
            xbuf[base + (size_t)(m0 + q * 4 + r) * 256 + nt * 16 + ln15] = (acc[nt][r] + bv) * mk[r];
        }
    }
}

// ---------------------------------------------------------------------------
// Fused GAT layer, 512 threads = 8 waves per (b,t) block.
//  A : x fp32 -> LDS; positions/mask -> LDS.
//  A3: self-loop edge-attr averages (loopS).
//  B : h = x@W split MFMA; wave pair (chunk=w>>1) splits n-dim (half=w&1).
//  C : h -> LDS (full 256 cols via pair).
//  D : a_src/a_dst (threads 0..255), w_e (threads 256..267).
//  E : wave pair per head: d-range split; softmax attention + message with
//      on-the-fly geometry recompute (no geo buffer).
//  F : x = relu(LN(msg + x_old)), 8 threads per row.
__global__ __launch_bounds__(512, 4) void k_gat(float* __restrict__ xbuf,
                                                const float* __restrict__ boxes,
                                                const float* __restrict__ maskp,
                                                const unsigned short* __restrict__ Bsw,
                                                const float* __restrict__ edgeW,
                                                const float* __restrict__ attS,
                                                const float* __restrict__ attD,
                                                const float* __restrict__ attE,
                                                const float* __restrict__ bias,
                                                const float* __restrict__ lns,
                                                const float* __restrict__ lnb) {
    int bt = blockIdx.x;
    size_t base = (size_t)bt * 64 * 256;
    __shared__ float XS[64 * 260];               // fp32 tile: x -> h -> msg
    __shared__ float pxS[64], pyS[64], vmS[64];
    __shared__ float loopS[64 * 4];
    __shared__ float asrcS[256], adstS[256], wES[12];
    __shared__ float alphaS[8 * 4 * 64];         // per-wave private 4x64
    int tid = threadIdx.x, lane = tid & 63, w = tid >> 6;
    int ln15 = lane & 15, q = lane >> 4;

    // Phase A: x -> LDS; positions
    for (int idx = tid; idx < 2048; idx += 512) {
        int m = idx >> 5, c8 = (idx & 31) * 8;
        float4 v0 = *(const float4*)&xbuf[base + m * 256 + c8];
        float4 v1 = *(const float4*)&xbuf[base + m * 256 + c8 + 4];
        *(float4*)&XS[m * 260 + c8] = v0;
        *(float4*)&XS[m * 260 + c8 + 4] = v1;
    }
    if (tid < 64) {
        const float* bx = boxes + (size_t)(bt * 64 + tid) * 5;
        pxS[tid] = bx[1];
        pyS[tid] = bx[2];
        vmS[tid] = maskp[bt * 64 + tid];
    }
    __syncthreads();

    // Phase A3: loop_attr averages. thread: d = tid>>3, s-range = (tid&7)*8..+8
    {
        int d = tid >> 3, part = tid & 7;
        float pxd = pxS[d], pyd = pyS[d];
        bool vd = vmS[d] > 0.5f;
        float deg = 0.f, s0 = 0.f, s1 = 0.f, s2 = 0.f;
        #pragma unroll
        for (int k = 0; k < 8; k++) {
            int s = part * 8 + k;
            float rx = pxd - pxS[s], ry = pyd - pyS[s];
            float dist = sqrtf(fmaxf(rx * rx + ry * ry, 1e-12f));
            bool adj = vd && (vmS[s] > 0.5f) && (dist < 0.3f) && (s != d);
            if (adj) { deg += 1.f; s0 += dist; s1 += rx; s2 += ry; }
        }
        #pragma unroll
        for (int off = 1; off < 8; off <<= 1) {
            deg += __shfl_xor(deg, off);
            s0  += __shfl_xor(s0, off);
            s1  += __shfl_xor(s1, off);
            s2  += __shfl_xor(s2, off);
        }
        if (part == 0) {
            float dg = fmaxf(deg, 1.f);
            loopS[d * 4 + 0] = s0 / dg;
            loopS[d * 4 + 1] = s1 / dg;
            loopS[d * 4 + 2] = s2 / dg;
        }
    }

    // Phase B: split MFMA. Wave pair: chunk rows [16*(w>>1), +16); n-half = w&1.
    int chunk = w >> 1, half = w & 1;
    int m0 = chunk * 16;
    f32x4 acc[8];
    #pragma unroll
    for (int ntl = 0; ntl < 8; ntl++) acc[ntl] = (f32x4){0.f, 0.f, 0.f, 0.f};
    {
        const float* arow = &XS[(m0 + ln15) * 260 + q * 8];
        for (int ks = 0; ks < 8; ks++) {
            float4 a0 = *(const float4*)&arow[ks * 32];
            float4 a1 = *(const float4*)&arow[ks * 32 + 4];
            bf16x8 ahi, alo;
            split8(a0, a1, ahi, alo);
            #pragma unroll
            for (int ntl = 0; ntl < 8; ntl++) {
                int nt = half * 8 + ntl;
                const unsigned short* fb = &Bsw[((size_t)(ks * 16 + nt) * 64 + lane) * 16];
                bf16x8 bhi = *(const bf16x8*)&fb[0];
                bf16x8 blo = *(const bf16x8*)&fb[8];
                acc[ntl] = __builtin_amdgcn_mfma_f32_16x16x32_bf16(ahi, bhi, acc[ntl], 0, 0, 0);
                acc[ntl] = __builtin_amdgcn_mfma_f32_16x16x32_bf16(alo, bhi, acc[ntl], 0, 0, 0);
                acc[ntl] = __builtin_amdgcn_mfma_f32_16x16x32_bf16(ahi, blo, acc[ntl], 0, 0, 0);
            }
        }
    }
    __syncthreads();   // all x reads done before h overwrites

    // Phase C: write h
    #pragma unroll
    for (int ntl = 0; ntl < 8; ntl++) {
        int nt = half * 8 + ntl;
        #pragma unroll
        for (int r = 0; r < 4; r++) {
            XS[(size_t)(m0 + q * 4 + r) * 260 + nt * 16 + ln15] = acc[ntl][r];
        }
    }
    __syncthreads();

    // Phase D: a_src/a_dst (threads 0..255); w_e (threads 256..267)
    if (tid < 256) {
        int hh = tid >> 6, mD = tid & 63;
        float s1 = 0.f, s2 = 0.f;
        const float* hr = &XS[mD * 260 + hh * 64];
        const float* pS = attS + hh * 64;
        const float* pD = attD + hh * 64;
        #pragma unroll
        for (int c = 0; c < 64; c += 4) {
            float4 hv = *(const float4*)&hr[c];
            float4 a1 = *(const float4*)&pS[c];
            float4 a2 = *(const float4*)&pD[c];
            s1 += dot4(hv, a1);
            s2 += dot4(hv, a2);
        }
        asrcS[hh * 64 + mD] = s1;
        adstS[hh * 64 + mD] = s2;
    } else if (tid < 268) {
        int e = (tid - 256) >> 2, h2 = (tid - 256) & 3;
        float sm = 0.f;
        for (int c = 0; c < 64; c++)
            sm += edgeW[e * 256 + h2 * 64 + c] * attE[h2 * 64 + c];
        wES[e * 4 + h2] = sm;
    }
    __syncthreads();

    // Phase E: wave pair per head h = w>>1; d-half = w&1. lane = source s.
    {
        int h = w >> 1, dhalf = w & 1;
        float hreg[64];
        #pragma unroll
        for (int ss = 0; ss < 64; ss++) hreg[ss] = XS[ss * 260 + h * 64 + lane];
        float px_l = pxS[lane], py_l = pyS[lane];
        bool v_l = vmS[lane] > 0.5f;
        float we0 = wES[0 * 4 + h], we1 = wES[1 * 4 + h], we2 = wES[2 * 4 + h];
        float a_s = asrcS[h * 64 + lane];
        float bv = bias[h * 64 + lane];
        __syncthreads();   // all h reads (hreg) done before msg overwrites

        float* aw = &alphaS[w * 256];   // wave-private 4x64
        for (int g = 0; g < 8; g++) {
            int dg = dhalf * 32 + g * 4;
            float lg[4], mx[4], ee[4], sm[4];
            #pragma unroll
            for (int i = 0; i < 4; i++) {
                int d = dg + i;
                float pxd = pxS[d], pyd = pyS[d];
                bool vd = vmS[d] > 0.5f;
                float rx = pxd - px_l, ry = pyd - py_l;
                float dist = sqrtf(fmaxf(rx * rx + ry * ry, 1e-12f));
                bool adj = vd && v_l && (dist < 0.3f) && (lane != d);
                bool self = (lane == d);
                float e0 = adj ? dist : (self ? loopS[d * 4 + 0] : 0.f);
                float e1 = adj ? rx   : (self ? loopS[d * 4 + 1] : 0.f);
                float e2 = adj ? ry   : (self ? loopS[d * 4 + 2] : 0.f);
                bool fa = adj || (self && vd);
                float l = a_s + adstS[h * 64 + d] + e0 * we0 + e1 * we1 + e2 * we2;
                l = l >= 0.f ? l : 0.2f * l;
                lg[i] = fa ? l : -1e9f;
                mx[i] = lg[i];
            }
            #pragma unroll
            for (int off = 32; off; off >>= 1) {
                #pragma unroll
                for (int i = 0; i < 4; i++) mx[i] = fmaxf(mx[i], __shfl_xor(mx[i], off));
            }
            #pragma unroll
            for (int i = 0; i < 4; i++) { ee[i] = __expf(lg[i] - mx[i]); sm[i] = ee[i]; }
            #pragma unroll
            for (int off = 32; off; off >>= 1) {
                #pragma unroll
                for (int i = 0; i < 4; i++) sm[i] += __shfl_xor(sm[i], off);
            }
            #pragma unroll
            for (int i = 0; i < 4; i++) aw[i * 64 + lane] = ee[i] / sm[i];
            // per-wave LDS is in-order; drain writes before broadcast reads
            __asm__ volatile("s_waitcnt lgkmcnt(0)" ::: "memory");
            float mc[4] = {0.f, 0.f, 0.f, 0.f};
            #pragma unroll
            for (int s4 = 0; s4 < 64; s4 += 4) {
                #pragma unroll
                for (int i = 0; i < 4; i++) {
                    float4 av = *(const float4*)&aw[i * 64 + s4];
                    mc[i] = fmaf(av.x, hreg[s4 + 0],
                            fmaf(av.y, hreg[s4 + 1],
                            fmaf(av.z, hreg[s4 + 2],
                            fmaf(av.w, hreg[s4 + 3], mc[i]))));
                }
            }
            #pragma unroll
            for (int i = 0; i < 4; i++)
                XS[(size_t)(dg + i) * 260 + h * 64 + lane] = mc[i] + bv;
        }
    }
    __syncthreads();

    // Phase F: x = relu(LN(msg + x_old)); 8 threads per row, 32 c each.
    {
        int mF = tid >> 3, q8 = tid & 7;
        size_t xrow = base + (size_t)mF * 256 + q8 * 32;
        const float* mrow = &XS[mF * 260 + q8 * 32];
        float sum = 0.f, sum2 = 0.f;
        #pragma unroll
        for (int j = 0; j < 32; j += 4) {
            float4 ms = *(const float4*)&mrow[j];
            float4 xo = *(const float4*)&xbuf[xrow + j];
            float v0 = ms.x + xo.x, v1 = ms.y + xo.y, v2 = ms.z + xo.z, v3 = ms.w + xo.w;
            sum  += v0 + v1 + v2 + v3;
            sum2 += v0*v0 + v1*v1 + v2*v2 + v3*v3;
        }
        #pragma unroll
        for (int off = 1; off < 8; off <<= 1) {
            sum  += __shfl_xor(sum, off);
            sum2 += __shfl_xor(sum2, off);
        }
        float mu = sum * (1.f / 256.f);
        float var = sum2 * (1.f / 256.f) - mu * mu;
        float rstd = rsqrtf(var + 1e-5f);
        #pragma unroll
        for (int j = 0; j < 32; j += 4) {
            float4 ms = *(const float4*)&mrow[j];
            float4 xo = *(const float4*)&xbuf[xrow + j];
            float4 sc = *(const float4*)&lns[q8 * 32 + j];
            float4 bb = *(const float4*)&lnb[q8 * 32 + j];
            float4 o;
            o.x = fmaxf((ms.x + xo.x - mu) * rstd * sc.x + bb.x, 0.f);
            o.y = fmaxf((ms.y + xo.y - mu) * rstd * sc.y + bb.y, 0.f);
            o.z = fmaxf((ms.z + xo.z - mu) * rstd * sc.z + bb.z, 0.f);
            o.w = fmaxf((ms.w + xo.w - mu) * rstd * sc.w + bb.w, 0.f);
            *(float4*)&xbuf[xrow + j] = o;
        }
    }
}

// ---------------------------------------------------------------------------
__global__ __launch_bounds__(256) void k_frame_temp(const float* __restrict__ xbuf,
                                                    const float* __restrict__ mask,
                                                    const float* __restrict__ tW,
                                                    const float* __restrict__ tb,
                                                    const float* __restrict__ pe,
                                                    float* __restrict__ ybuf) {
    int bt = blockIdx.x;
    int t = bt & 31;
    size_t base = (size_t)bt * 64 * 256;
    __shared__ float frS[256];
    __shared__ float nvS;
    int tid = threadIdx.x;
    if (tid == 0) {
        float nv = 0.f;
        for (int m = 0; m < 64; m++) nv += (mask[bt * 64 + m] > 0.5f) ? 1.f : 0.f;
        nvS = fmaxf(nv, 1.f);
    }
    float fr = 0.f;
    for (int m = 0; m < 64; m++) {
        float vmv = mask[bt * 64 + m] > 0.5f ? 1.f : 0.f;
        fr += xbuf[base + m * 256 + tid] * vmv;
    }
    __syncthreads();
    frS[tid] = fr / nvS;
    __syncthreads();
    float acc = tb[tid] + pe[t * 256 + tid];
    const float* wrow = tW + (size_t)tid * 256;
    for (int g = 0; g < 256; g += 4) {
        float4 f = *(const float4*)&frS[g];
        float4 wv = *(const float4*)&wrow[g];
        acc += dot4(f, wv);
    }
    ybuf[bt * 256 + tid] = acc;
}

// ---------------------------------------------------------------------------
__global__ __launch_bounds__(256) void k_ln_qkv(const float* __restrict__ ybuf,
                                                const float* __restrict__ ln_s,
                                                const float* __restrict__ ln_b,
                                                const float* __restrict__ qW,
                                                const float* __restrict__ qb,
                                                float* __restrict__ qkvbuf) {
    int bt = blockIdx.x, tid = threadIdx.x;
    __shared__ float zS[256];
    __shared__ float red[8];
    float yv = ybuf[bt * 256 + tid];
    float s = yv, s2 = yv * yv;
    block_reduce2(s, s2, red);
    float mu = s * (1.f / 256.f);
    float var = s2 * (1.f / 256.f) - mu * mu;
    float rstd = rsqrtf(var + 1e-5f);
    zS[tid] = (yv - mu) * rstd * ln_s[tid] + ln_b[tid];
    __syncthreads();
    for (int r = 0; r < 3; r++) {
        int j = r * 256 + tid;
        float acc = qb[j];
        const float* wrow = qW + (size_t)j * 256;
        for (int i = 0; i < 256; i += 4) {
            float4 z = *(const float4*)&zS[i];
            float4 wv = *(const float4*)&wrow[i];
            acc += dot4(z, wv);
        }
        qkvbuf[(size_t)bt * 768 + j] = acc;
    }
}

// ---------------------------------------------------------------------------
__global__ __launch_bounds__(64) void k_attn(const float* __restrict__ qkvbuf,
                                             float* __restrict__ obuf) {
    int blk = blockIdx.x;
    int b = blk >> 3, h = blk & 7;
    int tid = threadIdx.x;
    __shared__ float Ks[32 * 32], Vs[32 * 32];
    for (int idx = tid; idx < 1024; idx += 64) {
        int tk = idx >> 5, c = idx & 31;
        size_t qbase = ((size_t)(b * 32 + tk)) * 768 + h * 32 + c;
        Ks[idx] = qkvbuf[qbase + 256];
        Vs[idx] = qkvbuf[qbase + 512];
    }
    __syncthreads();
    if (tid < 32) {
        int tq = tid;
        float qv[32];
        size_t qb0 = ((size_t)(b * 32 + tq)) * 768 + h * 32;
        #pragma unroll
        for (int c = 0; c < 32; c++) qv[c] = qkvbuf[qb0 + c];
        float scr[32];
        float mx = -1e30f;
        #pragma unroll
        for (int tk = 0; tk < 32; tk++) {
            float dd = 0.f;
            #pragma unroll
            for (int c = 0; c < 32; c++) dd = fmaf(qv[c], Ks[tk * 32 + c], dd);
            dd *= 0.17677669529663687f;
            scr[tk] = dd;
            mx = fmaxf(mx, dd);
        }
        float sm = 0.f;
        #pragma unroll
        for (int tk = 0; tk < 32; tk++) { scr[tk] = __expf(scr[tk] - mx); sm += scr[tk]; }
        float inv = 1.f / sm;
        float o[32];
        #pragma unroll
        for (int c = 0; c < 32; c++) o[c] = 0.f;
        #pragma unroll
        for (int tk = 0; tk < 32; tk++) {
            float a = scr[tk] * inv;
            #pragma unroll
            for (int c = 0; c < 32; c++) o[c] = fmaf(a, Vs[tk * 32 + c], o[c]);
        }
        size_t ob = ((size_t)(b * 32 + tq)) * 256 + h * 32;
        #pragma unroll
        for (int c = 0; c < 32; c++) obuf[ob + c] = o[c];
    }
}

// ---------------------------------------------------------------------------
__global__ __launch_bounds__(256) void k_attn_out(const float* __restrict__ obuf,
                                                  const float* __restrict__ W,
                                                  const float* __restrict__ bvec,
                                                  float* __restrict__ ybuf) {
    int bt = blockIdx.x, tid = threadIdx.x;
    __shared__ float oS[256];
    oS[tid] = obuf[bt * 256 + tid];
    __syncthreads();
    float acc = bvec[tid];
    const float* wrow = W + (size_t)tid * 256;
    for (int i = 0; i < 256; i += 4) {
        float4 o = *(const float4*)&oS[i];
        float4 wv = *(const float4*)&wrow[i];
        acc += dot4(o, wv);
    }
    ybuf[bt * 256 + tid] += acc;
}

// ---------------------------------------------------------------------------
__global__ __launch_bounds__(256) void k_ff(float* __restrict__ ybuf,
                                            const float* __restrict__ ln_s,
                                            const float* __restrict__ ln_b,
                                            const float* __restrict__ W1,
                                            const float* __restrict__ b1,
                                            const float* __restrict__ W2,
                                            const float* __restrict__ b2) {
    int bt = blockIdx.x, tid = threadIdx.x;
    __shared__ float zS[256];
    __shared__ float fS[512];
    __shared__ float red[8];
    float yv = ybuf[bt * 256 + tid];
    float s = yv, s2 = yv * yv;
    block_reduce2(s, s2, red);
    float mu = s * (1.f / 256.f);
    float var = s2 * (1.f / 256.f) - mu * mu;
    float rstd = rsqrtf(var + 1e-5f);
    zS[tid] = (yv - mu) * rstd * ln_s[tid] + ln_b[tid];
    __syncthreads();
    for (int r = 0; r < 2; r++) {
        int j = r * 256 + tid;
        float acc = b1[j];
        const float* wrow = W1 + (size_t)j * 256;
        for (int i = 0; i < 256; i += 4) {
            float4 z = *(const float4*)&zS[i];
            float4 wv = *(const float4*)&wrow[i];
            acc += dot4(z, wv);
        }
        fS[j] = fmaxf(acc, 0.f);
    }
    __syncthreads();
    float acc = b2[tid];
    const float* wrow = W2 + (size_t)tid * 512;
    for (int j = 0; j < 512; j += 4) {
        float4 f = *(const float4*)&fS[j];
        float4 wv = *(const float4*)&wrow[j];
        acc += dot4(f, wv);
    }
    ybuf[bt * 256 + tid] = yv + acc;
}

// ---------------------------------------------------------------------------
__global__ __launch_bounds__(256) void k_pool_out(const float* __restrict__ ybuf,
                                                  const float* __restrict__ pW,
                                                  const float* __restrict__ pb,
                                                  const float* __restrict__ oW,
                                                  const float* __restrict__ ob,
                                                  const float* __restrict__ lns,
                                                  const float* __restrict__ lnb,
                                                  float* __restrict__ dout) {
    int b = blockIdx.x, tid = threadIdx.x;
    __shared__ float redP[256];
    __shared__ float wS[32];
    __shared__ float pS[256];
    __shared__ float red[8];
    int tq = tid >> 3, part = tid & 7;
    float partial = 0.f;
    {
        const float* yrow = ybuf + ((size_t)(b * 32 + tq)) * 256 + part * 32;
        const float* pwp = pW + part * 32;
        #pragma unroll
        for (int j = 0; j < 32; j += 4) {
            float4 yv = *(const float4*)&yrow[j];
            float4 wv = *(const float4*)&pwp[j];
            partial += dot4(yv, wv);
        }
    }
    redP[tid] = partial;
    __syncthreads();
    if (tid < 32) {
        float s = pb[0];
        for (int p = 0; p < 8; p++) s += redP[tid * 8 + p];
        float mx = s;
        #pragma unroll
        for (int off = 16; off; off >>= 1) mx = fmaxf(mx, __shfl_xor(mx, off));
        float e = __expf(s - mx);
        float sm = e;
        #pragma unroll
        for (int off = 16; off; off >>= 1) sm += __shfl_xor(sm, off);
        wS[tid] = e / sm;
    }
    __syncthreads();
    float p = 0.f;
    for (int t = 0; t < 32; t++) p += ybuf[((size_t)(b * 32 + t)) * 256 + tid] * wS[t];
    pS[tid] = p;
    __syncthreads();
    float accs[2];
    for (int r = 0; r < 2; r++) {
        int j = r * 256 + tid;
        float acc = ob[j];
        const float* wrow = oW + (size_t)j * 256;
        for (int g = 0; g < 256; g += 4) {
            float4 pv = *(const float4*)&pS[g];
            float4 wv = *(const float4*)&wrow[g];
            acc += dot4(pv, wv);
        }
        accs[r] = acc;
    }
    float s = accs[0] + accs[1];
    float s2 = accs[0] * accs[0] + accs[1] * accs[1];
    block_reduce2(s, s2, red);
    float mu = s * (1.f / 512.f);
    float var = s2 * (1.f / 512.f) - mu * mu;
    float rstd = rsqrtf(var + 1e-5f);
    dout[b * 512 + tid]       = fmaxf((accs[0] - mu) * rstd * lns[tid] + lnb[tid], 0.f);
    dout[b * 512 + tid + 256] = fmaxf((accs[1] - mu) * rstd * lns[tid + 256] + lnb[tid + 256], 0.f);
}

// ---------------------------------------------------------------------------
extern "C" void kernel_launch(void* const* d_in, const int* in_sizes, int n_in,
                              void* d_out, int out_size, void* d_ws, size_t ws_size,
                              hipStream_t stream) {
    const float* drone_feats = (const float*)d_in[0];
    const float* boxes       = (const float*)d_in[1];
    const float* drone_mask  = (const float*)d_in[2];
    const float* in_proj_W   = (const float*)d_in[3];
    const float* in_proj_b   = (const float*)d_in[4];
    const float* gat_lin_W   = (const float*)d_in[5];
    const float* gat_edge_W  = (const float*)d_in[6];
    const float* gat_att_src = (const float*)d_in[7];
    const float* gat_att_dst = (const float*)d_in[8];
    const float* gat_att_edge= (const float*)d_in[9];
    const float* gat_bias    = (const float*)d_in[10];
    const float* gat_ln_s    = (const float*)d_in[11];
    const float* gat_ln_b    = (const float*)d_in[12];
    const float* temp_W      = (const float*)d_in[13];
    const float* temp_b      = (const float*)d_in[14];
    const float* pos_emb     = (const float*)d_in[15];
    const float* qkv_W       = (const float*)d_in[16];
    const float* qkv_b       = (const float*)d_in[17];
    const float* attn_out_W  = (const float*)d_in[18];
    const float* attn_out_b  = (const float*)d_in[19];
    const float* ln1_s       = (const float*)d_in[20];
    const float* ln1_b       = (const float*)d_in[21];
    const float* ln2_s       = (const float*)d_in[22];
    const float* ln2_b       = (const float*)d_in[23];
    const float* ff1_W       = (const float*)d_in[24];
    const float* ff1_b       = (const float*)d_in[25];
    const float* ff2_W       = (const float*)d_in[26];
    const float* ff2_b       = (const float*)d_in[27];
    const float* pool_W      = (const float*)d_in[28];
    const float* pool_b      = (const float*)d_in[29];
    const float* out_W       = (const float*)d_in[30];
    const float* out_b       = (const float*)d_in[31];
    const float* out_ln_s    = (const float*)d_in[32];
    const float* out_ln_b    = (const float*)d_in[33];
    float* out = (float*)d_out;

    float* ws = (float*)d_ws;
    float* xbuf = ws;
    size_t off = (size_t)BT * 64 * 256;
    unsigned short* Bsw = (unsigned short*)(ws + off); off += 4 * 16384 * 16 / 2;  // hi/lo bf16
    float* ybuf   = ws + off; off += (size_t)BT * 256;
    float* qkvbuf = ws + off; off += (size_t)BT * 768;
    float* obuf   = ws + off; off += (size_t)BT * 256;

    k_prep<<<dim3(256), dim3(256), 0, stream>>>(in_proj_W, gat_lin_W, Bsw);
    k_inproj<<<dim3(BT), dim3(256), 0, stream>>>(drone_feats, Bsw, in_proj_b, drone_mask, xbuf);
    for (int l = 0; l < 3; l++) {
        k_gat<<<dim3(BT), dim3(512), 0, stream>>>(xbuf, boxes, drone_mask,
            Bsw + (size_t)(1 + l) * 16384 * 16, gat_edge_W + (size_t)l * 768,
            gat_att_src + (size_t)l * 256, gat_att_dst + (size_t)l * 256,
            gat_att_edge + (size_t)l * 256, gat_bias + (size_t)l * 256,
            gat_ln_s + (size_t)l * 256, gat_ln_b + (size_t)l * 256);
    }
    k_frame_temp<<<dim3(BT), dim3(256), 0, stream>>>(xbuf, drone_mask, temp_W, temp_b, pos_emb, ybuf);
    for (int l = 0; l < 2; l++) {
        k_ln_qkv<<<dim3(BT), dim3(256), 0, stream>>>(ybuf, ln1_s + l * 256, ln1_b + l * 256,
            qkv_W + (size_t)l * 768 * 256, qkv_b + l * 768, qkvbuf);
        k_attn<<<dim3(512), dim3(64), 0, stream>>>(qkvbuf, obuf);
        k_attn_out<<<dim3(BT), dim3(256), 0, stream>>>(obuf,
            attn_out_W + (size_t)l * 65536, attn_out_b + l * 256, ybuf);
        k_ff<<<dim3(BT), dim3(256), 0, stream>>>(ybuf, ln2_s + l * 256, ln2_b + l * 256,
            ff1_W + (size_t)l * 131072, ff1_b + l * 512,
            ff2_W + (size_t)l * 131072, ff2_b + l * 256);
    }
    k_pool_out<<<dim3(64), dim3(256), 0, stream>>>(ybuf, pool_W, pool_b, out_W, out_b,
                                                   out_ln_s, out_ln_b, out);
}

// Round 6
// 1245.658 us; speedup vs baseline: 2.5911x; 1.9170x over previous
//
#include <hip/hip_runtime.h>
#include <math.h>

#define BT 2048

typedef __attribute__((ext_vector_type(8))) short bf16x8;
typedef __attribute__((ext_vector_type(4))) float f32x4;

__device__ inline unsigned short f2bf(float f) {
    union { float f; unsigned u; } v; v.f = f;
    unsigned r = (v.u >> 16) & 1u;
    return (unsigned short)((v.u + 0x7FFFu + r) >> 16);
}
__device__ inline float bf2f(unsigned short s) {
    union { unsigned u; float f; } v; v.u = ((unsigned)s) << 16;
    return v.f;
}

__device__ inline float dot4(const float4 a, const float4 b) {
    return fmaf(a.x, b.x, fmaf(a.y, b.y, fmaf(a.z, b.z, a.w * b.w)));
}

union F8 { float4 v2[2]; float f[8]; };

// ---------------------------------------------------------------------------
// Pre-swizzle weights into MFMA B-fragment order, SPLIT bf16 hi/lo.
__global__ __launch_bounds__(256) void k_prep(const float* __restrict__ inW,
                                              const float* __restrict__ gatW,
                                              unsigned short* __restrict__ dst) {
    int gid = blockIdx.x * 256 + threadIdx.x;   // 0..65535
    int mat = gid >> 14;
    int r   = gid & 16383;
    int ks  = r >> 10;
    int nt  = (r >> 6) & 15;
    int lane = r & 63;
    int ln15 = lane & 15, q = lane >> 4;
    int n  = nt * 16 + ln15;
    int k0 = ks * 32 + q * 8;
    const float* src; bool tr;
    if (mat == 0) { src = inW; tr = true; }
    else          { src = gatW + (size_t)(mat - 1) * 65536; tr = false; }
    unsigned short* d = dst + ((size_t)mat * 16384 + r) * 16;
    #pragma unroll
    for (int j = 0; j < 8; j++) {
        float v = tr ? src[n * 256 + k0 + j] : src[(size_t)(k0 + j) * 256 + n];
        unsigned short hi = f2bf(v);
        d[j]     = hi;
        d[8 + j] = f2bf(v - bf2f(hi));
    }
}

// split a float8 (two float4) into hi/lo bf16x8 fragments
__device__ inline void split8(const float4 a0, const float4 a1, bf16x8& hi, bf16x8& lo) {
    union { bf16x8 v; unsigned short u[8]; } H, L;
    float f[8] = {a0.x, a0.y, a0.z, a0.w, a1.x, a1.y, a1.z, a1.w};
    #pragma unroll
    for (int j = 0; j < 8; j++) {
        H.u[j] = f2bf(f[j]);
        L.u[j] = f2bf(f[j] - bf2f(H.u[j]));
    }
    hi = H.v; lo = L.v;
}

// ---------------------------------------------------------------------------
// in_proj via split MFMA: x[bt] = (feats[bt] @ W^T + b) * mask
__global__ __launch_bounds__(256, 3) void k_inproj(const float* __restrict__ feats,
                                                   const unsigned short* __restrict__ Bsw,
                                                   const float* __restrict__ bias,
                                                   const float* __restrict__ mask,
                                                   float* __restrict__ xbuf) {
    int bt = blockIdx.x;
    size_t base = (size_t)bt * 64 * 256;
    int lane = threadIdx.x & 63, w = threadIdx.x >> 6;
    int ln15 = lane & 15, q = lane >> 4;
    int m0 = w * 16;
    f32x4 acc[16];
    #pragma unroll
    for (int nt = 0; nt < 16; nt++) acc[nt] = (f32x4){0.f, 0.f, 0.f, 0.f};
    const float* arow = feats + base + (size_t)(m0 + ln15) * 256 + q * 8;
    for (int ks = 0; ks < 8; ks++) {
        float4 a0 = *(const float4*)&arow[ks * 32];
        float4 a1 = *(const float4*)&arow[ks * 32 + 4];
        bf16x8 ahi, alo;
        split8(a0, a1, ahi, alo);
        #pragma unroll
        for (int nt = 0; nt < 16; nt++) {
            const unsigned short* fb = &Bsw[((size_t)(ks * 16 + nt) * 64 + lane) * 16];
            bf16x8 bhi = *(const bf16x8*)&fb[0];
            bf16x8 blo = *(const bf16x8*)&fb[8];
            acc[nt] = __builtin_amdgcn_mfma_f32_16x16x32_bf16(ahi, bhi, acc[nt], 0, 0, 0);
            acc[nt] = __builtin_amdgcn_mfma_f32_16x16x32_bf16(alo, bhi, acc[nt], 0, 0, 0);
            acc[nt] = __builtin_amdgcn_mfma_f32_16x16x32_bf16(ahi, blo, acc[nt], 0, 0, 0);
        }
    }
    float mk[4];
    #pragma unroll
    for (int r = 0; r < 4; r++) mk[r] = mask[bt * 64 + m0 + q * 4 + r] > 0.5f ? 1.f : 0.f;
    #pragma unroll
    for (int nt = 0; nt < 16; nt++) {
        float bv = bias[nt * 16 + ln15];
        #pragma unroll
        for (int r = 0; r < 4; r++) {
            xbuf[base + (size_t)(m0 + q * 4 + r) * 256 + nt * 16 + ln15] = (acc[nt][r] + bv) * mk[r];
        }
    }
}

// ---------------------------------------------------------------------------
// Fused GAT layer, 512 threads = 8 waves per (b,t) block.
//  A : positions/mask -> LDS; wES; A3: self-loop averages.
//  B : h = x@W split MFMA (x direct from global). Wave pair: rows chunk*16..+16,
//      n-half = w&1.
//  C : h -> hT LDS bf16 hi/lo c-major; PER-HEAD a_src/a_dst partials from regs
//      (lane channel c = half*128 + ntl*16 + ln15 -> head = half*2 + (ntl>>2)).
//  E : wave = (head, d-half): logits in MFMA A-frag layout; softmax via 2
//      shuffle rounds; alpha hi/lo A-frags in regs; P·H via MFMA.
//  F : LN over c (4 heads' partials via LDS) + relu, write x in place.
__global__ __launch_bounds__(512, 2) void k_gat(float* __restrict__ xbuf,
                                                const float* __restrict__ boxes,
                                                const float* __restrict__ maskp,
                                                const unsigned short* __restrict__ Bsw,
                                                const float* __restrict__ edgeW,
                                                const float* __restrict__ attS,
                                                const float* __restrict__ attD,
                                                const float* __restrict__ attE,
                                                const float* __restrict__ bias,
                                                const float* __restrict__ lns,
                                                const float* __restrict__ lnb) {
    int bt = blockIdx.x;
    size_t base = (size_t)bt * 64 * 256;
    __shared__ unsigned short hT[256 * 136];     // h bf16: [c][0..63]=hi, [64..127]=lo
    __shared__ float pxS[64], pyS[64], vmS[64];
    __shared__ float loopS[64 * 3];
    __shared__ float asrcS[4][64], adstS[4][64]; // PER-HEAD [h][m]
    __shared__ float wES[12];
    __shared__ float sumsS[64][8];               // [d][head*2 + {sum,sum2}]
    __shared__ float mrsS[64][2];
    int tid = threadIdx.x, lane = tid & 63, w = tid >> 6;
    int ln15 = lane & 15, q = lane >> 4;

    // Phase A: positions + wES
    if (tid < 64) {
        const float* bx = boxes + (size_t)(bt * 64 + tid) * 5;
        pxS[tid] = bx[1];
        pyS[tid] = bx[2];
        vmS[tid] = maskp[bt * 64 + tid];
    } else if (tid < 76) {
        int e = (tid - 64) >> 2, h2 = (tid - 64) & 3;
        float sm = 0.f;
        for (int c = 0; c < 64; c++)
            sm += edgeW[e * 256 + h2 * 64 + c] * attE[h2 * 64 + c];
        wES[e * 4 + h2] = sm;
    }
    __syncthreads();

    // Phase A3: self-loop edge-attr averages
    {
        int d = tid >> 3, part = tid & 7;
        float pxd = pxS[d], pyd = pyS[d];
        bool vd = vmS[d] > 0.5f;
        float deg = 0.f, s0 = 0.f, s1 = 0.f, s2 = 0.f;
        #pragma unroll
        for (int k = 0; k < 8; k++) {
            int s = part * 8 + k;
            float rx = pxd - pxS[s], ry = pyd - pyS[s];
            float dist = sqrtf(fmaxf(rx * rx + ry * ry, 1e-12f));
            bool adj = vd && (vmS[s] > 0.5f) && (dist < 0.3f) && (s != d);
            if (adj) { deg += 1.f; s0 += dist; s1 += rx; s2 += ry; }
        }
        #pragma unroll
        for (int off = 1; off < 8; off <<= 1) {
            deg += __shfl_xor(deg, off);
            s0  += __shfl_xor(s0, off);
            s1  += __shfl_xor(s1, off);
            s2  += __shfl_xor(s2, off);
        }
        if (part == 0) {
            float dg = fmaxf(deg, 1.f);
            loopS[d * 3 + 0] = s0 / dg;
            loopS[d * 3 + 1] = s1 / dg;
            loopS[d * 3 + 2] = s2 / dg;
        }
    }

    // Phase B: split MFMA h = x@W. chunk rows, n-half.
    int chunk = w >> 1, half = w & 1;
    int m0 = chunk * 16;
    f32x4 acc[8];
    #pragma unroll
    for (int ntl = 0; ntl < 8; ntl++) acc[ntl] = (f32x4){0.f, 0.f, 0.f, 0.f};
    {
        const float* arow = xbuf + base + (size_t)(m0 + ln15) * 256 + q * 8;
        for (int ks = 0; ks < 8; ks++) {
            float4 a0 = *(const float4*)&arow[ks * 32];
            float4 a1 = *(const float4*)&arow[ks * 32 + 4];
            bf16x8 ahi, alo;
            split8(a0, a1, ahi, alo);
            #pragma unroll
            for (int ntl = 0; ntl < 8; ntl++) {
                int nt = half * 8 + ntl;
                const unsigned short* fb = &Bsw[((size_t)(ks * 16 + nt) * 64 + lane) * 16];
                bf16x8 bhi = *(const bf16x8*)&fb[0];
                bf16x8 blo = *(const bf16x8*)&fb[8];
                acc[ntl] = __builtin_amdgcn_mfma_f32_16x16x32_bf16(ahi, bhi, acc[ntl], 0, 0, 0);
                acc[ntl] = __builtin_amdgcn_mfma_f32_16x16x32_bf16(alo, bhi, acc[ntl], 0, 0, 0);
                acc[ntl] = __builtin_amdgcn_mfma_f32_16x16x32_bf16(ahi, blo, acc[ntl], 0, 0, 0);
            }
        }
    }

    // Phase C: hT (bf16 hi/lo, c-major) + PER-HEAD a_src/a_dst partials.
    // Lane channel c = half*128 + ntl*16 + ln15 -> head hh2 = half*2 + (ntl>>2).
    {
        float pS_[2][4] = {{0.f,0.f,0.f,0.f},{0.f,0.f,0.f,0.f}};
        float pD_[2][4] = {{0.f,0.f,0.f,0.f},{0.f,0.f,0.f,0.f}};
        #pragma unroll
        for (int ntl = 0; ntl < 8; ntl++) {
            int c = (half * 8 + ntl) * 16 + ln15;
            int hh = ntl >> 2;   // head-within-half
            float aS = attS[c], aD = attD[c];
            #pragma unroll
            for (int r = 0; r < 4; r++) {
                float v = acc[ntl][r];
                pS_[hh][r] = fmaf(v, aS, pS_[hh][r]);
                pD_[hh][r] = fmaf(v, aD, pD_[hh][r]);
                unsigned short hi = f2bf(v);
                unsigned short lo = f2bf(v - bf2f(hi));
                int s = m0 + q * 4 + r;
                hT[(size_t)c * 136 + s] = hi;
                hT[(size_t)c * 136 + 64 + s] = lo;
            }
        }
        #pragma unroll
        for (int off = 1; off < 16; off <<= 1) {
            #pragma unroll
            for (int hh = 0; hh < 2; hh++)
                #pragma unroll
                for (int r = 0; r < 4; r++) {
                    pS_[hh][r] += __shfl_xor(pS_[hh][r], off);
                    pD_[hh][r] += __shfl_xor(pD_[hh][r], off);
                }
        }
        if (ln15 == 0) {
            #pragma unroll
            for (int hh = 0; hh < 2; hh++)
                #pragma unroll
                for (int r = 0; r < 4; r++) {
                    asrcS[half * 2 + hh][m0 + q * 4 + r] = pS_[hh][r];
                    adstS[half * 2 + hh][m0 + q * 4 + r] = pD_[hh][r];
                }
        }
    }
    __syncthreads();

    // Phase E: logits in A-frag layout, softmax, alpha hi/lo frags, P·H MFMA.
    int head = w >> 1;
    int base_d = (w & 1) * 32;
    f32x4 macc[2][4];
    #pragma unroll
    for (int t = 0; t < 2; t++)
        #pragma unroll
        for (int ct = 0; ct < 4; ct++) macc[t][ct] = (f32x4){0.f, 0.f, 0.f, 0.f};
    {
        float pxd[2], pyd[2], adstv[2], lp0[2], lp1[2], lp2[2];
        int dcur[2];
        bool vdv[2];
        #pragma unroll
        for (int t = 0; t < 2; t++) {
            int d = base_d + t * 16 + ln15;
            dcur[t] = d;
            pxd[t] = pxS[d]; pyd[t] = pyS[d];
            vdv[t] = vmS[d] > 0.5f;
            adstv[t] = adstS[head][d];
            lp0[t] = loopS[d * 3 + 0];
            lp1[t] = loopS[d * 3 + 1];
            lp2[t] = loopS[d * 3 + 2];
        }
        float we0 = wES[head], we1 = wES[4 + head], we2 = wES[8 + head];

        float lg[2][16];
        #pragma unroll
        for (int ks = 0; ks < 2; ks++) {
            int s0 = ks * 32 + q * 8;
            F8 PX, PY, VM, AS;
            PX.v2[0] = *(const float4*)&pxS[s0]; PX.v2[1] = *(const float4*)&pxS[s0 + 4];
            PY.v2[0] = *(const float4*)&pyS[s0]; PY.v2[1] = *(const float4*)&pyS[s0 + 4];
            VM.v2[0] = *(const float4*)&vmS[s0]; VM.v2[1] = *(const float4*)&vmS[s0 + 4];
            AS.v2[0] = *(const float4*)&asrcS[head][s0];
            AS.v2[1] = *(const float4*)&asrcS[head][s0 + 4];
            #pragma unroll
            for (int j = 0; j < 8; j++) {
                int s = s0 + j;
                float vsf = VM.f[j];
                #pragma unroll
                for (int t = 0; t < 2; t++) {
                    float rx = pxd[t] - PX.f[j], ry = pyd[t] - PY.f[j];
                    float dist = sqrtf(fmaxf(rx * rx + ry * ry, 1e-12f));
                    bool self = (s == dcur[t]);
                    bool adj = vdv[t] && (vsf > 0.5f) && (dist < 0.3f) && !self;
                    float e0 = adj ? dist : (self ? lp0[t] : 0.f);
                    float e1 = adj ? rx   : (self ? lp1[t] : 0.f);
                    float e2 = adj ? ry   : (self ? lp2[t] : 0.f);
                    bool fa = adj || (self && vdv[t]);
                    float l = AS.f[j] + adstv[t] + e0 * we0 + e1 * we1 + e2 * we2;
                    l = l >= 0.f ? l : 0.2f * l;
                    lg[t][ks * 8 + j] = fa ? l : -1e9f;
                }
            }
        }

        // softmax over s (in-lane 16 + xor16/xor32 over q) + alpha frags
        bf16x8 ah[2][2], al[2][2];
        #pragma unroll
        for (int t = 0; t < 2; t++) {
            float mx = lg[t][0];
            #pragma unroll
            for (int j = 1; j < 16; j++) mx = fmaxf(mx, lg[t][j]);
            mx = fmaxf(mx, __shfl_xor(mx, 16));
            mx = fmaxf(mx, __shfl_xor(mx, 32));
            float ee[16], sm = 0.f;
            #pragma unroll
            for (int j = 0; j < 16; j++) { ee[j] = __expf(lg[t][j] - mx); sm += ee[j]; }
            sm += __shfl_xor(sm, 16);
            sm += __shfl_xor(sm, 32);
            float inv = 1.f / sm;
            #pragma unroll
            for (int ks2 = 0; ks2 < 2; ks2++) {
                union { bf16x8 v; unsigned short u[8]; } H, L;
                #pragma unroll
                for (int j = 0; j < 8; j++) {
                    float a = ee[ks2 * 8 + j] * inv;
                    unsigned short hi = f2bf(a);
                    H.u[j] = hi;
                    L.u[j] = f2bf(a - bf2f(hi));
                }
                ah[t][ks2] = H.v; al[t][ks2] = L.v;
            }
        }

        // P·H MFMA: msg[d][c] for d in base_d..+32, c in head*64..+64
        #pragma unroll
        for (int t = 0; t < 2; t++) {
            #pragma unroll
            for (int ks2 = 0; ks2 < 2; ks2++) {
                #pragma unroll
                for (int ct = 0; ct < 4; ct++) {
                    const unsigned short* hb =
                        &hT[(size_t)(head * 64 + ct * 16 + ln15) * 136 + ks2 * 32 + q * 8];
                    bf16x8 bhi = *(const bf16x8*)&hb[0];
                    bf16x8 blo = *(const bf16x8*)&hb[64];
                    macc[t][ct] = __builtin_amdgcn_mfma_f32_16x16x32_bf16(ah[t][ks2], bhi, macc[t][ct], 0, 0, 0);
                    macc[t][ct] = __builtin_amdgcn_mfma_f32_16x16x32_bf16(al[t][ks2], bhi, macc[t][ct], 0, 0, 0);
                    macc[t][ct] = __builtin_amdgcn_mfma_f32_16x16x32_bf16(ah[t][ks2], blo, macc[t][ct], 0, 0, 0);
                }
            }
        }
    }

    // Phase F: LN(msg + bias + x_old) + relu. Each wave owns (head c-range, d-half).
    {
        float bsv[4], scv[4], bbv[4];
        #pragma unroll
        for (int ct = 0; ct < 4; ct++) {
            int c = head * 64 + ct * 16 + ln15;
            bsv[ct] = bias[c];
            scv[ct] = lns[c];
            bbv[ct] = lnb[c];
        }
        float xo[2][4][4];
        #pragma unroll
        for (int t = 0; t < 2; t++)
            #pragma unroll
            for (int r = 0; r < 4; r++) {
                int d = base_d + t * 16 + q * 4 + r;
                #pragma unroll
                for (int ct = 0; ct < 4; ct++)
                    xo[t][ct][r] = xbuf[base + (size_t)d * 256 + head * 64 + ct * 16 + ln15];
            }
        float ps[8], ps2[8];
        #pragma unroll
        for (int t = 0; t < 2; t++)
            #pragma unroll
            for (int r = 0; r < 4; r++) {
                float s = 0.f, s2 = 0.f;
                #pragma unroll
                for (int ct = 0; ct < 4; ct++) {
                    float v = macc[t][ct][r] + xo[t][ct][r] + bsv[ct];
                    s += v; s2 += v * v;
                }
                ps[t * 4 + r] = s; ps2[t * 4 + r] = s2;
            }
        #pragma unroll
        for (int off = 1; off < 16; off <<= 1) {
            #pragma unroll
            for (int i = 0; i < 8; i++) {
                ps[i]  += __shfl_xor(ps[i], off);
                ps2[i] += __shfl_xor(ps2[i], off);
            }
        }
        if (ln15 == 0) {
            #pragma unroll
            for (int t = 0; t < 2; t++)
                #pragma unroll
                for (int r = 0; r < 4; r++) {
                    int d = base_d + t * 16 + q * 4 + r;
                    sumsS[d][head * 2 + 0] = ps[t * 4 + r];
                    sumsS[d][head * 2 + 1] = ps2[t * 4 + r];
                }
        }
        __syncthreads();
        if (tid < 64) {
            float S  = sumsS[tid][0] + sumsS[tid][2] + sumsS[tid][4] + sumsS[tid][6];
            float S2 = sumsS[tid][1] + sumsS[tid][3] + sumsS[tid][5] + sumsS[tid][7];
            float mu = S * (1.f / 256.f);
            float var = S2 * (1.f / 256.f) - mu * mu;
            mrsS[tid][0] = mu;
            mrsS[tid][1] = rsqrtf(var + 1e-5f);
        }
        __syncthreads();
        #pragma unroll
        for (int t = 0; t < 2; t++)
            #pragma unroll
            for (int r = 0; r < 4; r++) {
                int d = base_d + t * 16 + q * 4 + r;
                float mu = mrsS[d][0], rs = mrsS[d][1];
                #pragma unroll
                for (int ct = 0; ct < 4; ct++) {
                    float v = (macc[t][ct][r] + xo[t][ct][r] + bsv[ct] - mu) * rs * scv[ct] + bbv[ct];
                    xbuf[base + (size_t)d * 256 + head * 64 + ct * 16 + ln15] = fmaxf(v, 0.f);
                }
            }
    }
}

// ---------------------------------------------------------------------------
// frame + temp proj, 4 tokens per block (weight reuse + ILP)
__global__ __launch_bounds__(256) void k_frame_temp4(const float* __restrict__ xbuf,
                                                     const float* __restrict__ mask,
                                                     const float* __restrict__ tW,
                                                     const float* __restrict__ tb,
                                                     const float* __restrict__ pe,
                                                     float* __restrict__ ybuf) {
    int b4 = blockIdx.x;   // 0..511
    int tid = threadIdx.x;
    __shared__ float frS[4][256];
    __shared__ float nvS[4];
    if (tid < 4) {
        int bt = b4 * 4 + tid;
        float nv = 0.f;
        for (int m = 0; m < 64; m++) nv += (mask[bt * 64 + m] > 0.5f) ? 1.f : 0.f;
        nvS[tid] = fmaxf(nv, 1.f);
    }
    float fr[4] = {0.f, 0.f, 0.f, 0.f};
    for (int m = 0; m < 64; m++) {
        #pragma unroll
        for (int t = 0; t < 4; t++) {
            int bt = b4 * 4 + t;
            float vmv = mask[bt * 64 + m] > 0.5f ? 1.f : 0.f;
            fr[t] += xbuf[((size_t)bt * 64 + m) * 256 + tid] * vmv;
        }
    }
    __syncthreads();
    #pragma unroll
    for (int t = 0; t < 4; t++) frS[t][tid] = fr[t] / nvS[t];
    __syncthreads();
    float acc[4];
    #pragma unroll
    for (int t = 0; t < 4; t++) acc[t] = tb[tid] + pe[((b4 * 4 + t) & 31) * 256 + tid];
    const float* wrow = tW + (size_t)tid * 256;
    for (int g = 0; g < 256; g += 4) {
        float4 wv = *(const float4*)&wrow[g];
        #pragma unroll
        for (int t = 0; t < 4; t++) acc[t] += dot4(*(const float4*)&frS[t][g], wv);
    }
    #pragma unroll
    for (int t = 0; t < 4; t++) ybuf[(size_t)(b4 * 4 + t) * 256 + tid] = acc[t];
}

// ---------------------------------------------------------------------------
// LN1 + qkv, 4 tokens per block; wave-per-token LN.
__global__ __launch_bounds__(256) void k_ln_qkv4(const float* __restrict__ ybuf,
                                                 const float* __restrict__ ln_s,
                                                 const float* __restrict__ ln_b,
                                                 const float* __restrict__ qW,
                                                 const float* __restrict__ qb,
                                                 float* __restrict__ qkvbuf) {
    int b4 = blockIdx.x, tid = threadIdx.x;
    int lane = tid & 63, wv = tid >> 6;
    __shared__ float zS[4][256];
    {
        int bt = b4 * 4 + wv;
        float4 yv = *(const float4*)&ybuf[(size_t)bt * 256 + lane * 4];
        float s = yv.x + yv.y + yv.z + yv.w;
        float s2 = yv.x * yv.x + yv.y * yv.y + yv.z * yv.z + yv.w * yv.w;
        #pragma unroll
        for (int off = 1; off < 64; off <<= 1) { s += __shfl_xor(s, off); s2 += __shfl_xor(s2, off); }
        float mu = s * (1.f / 256.f);
        float var = s2 * (1.f / 256.f) - mu * mu;
        float rstd = rsqrtf(var + 1e-5f);
        float4 ls = *(const float4*)&ln_s[lane * 4];
        float4 lb = *(const float4*)&ln_b[lane * 4];
        float4 z;
        z.x = (yv.x - mu) * rstd * ls.x + lb.x;
        z.y = (yv.y - mu) * rstd * ls.y + lb.y;
        z.z = (yv.z - mu) * rstd * ls.z + lb.z;
        z.w = (yv.w - mu) * rstd * ls.w + lb.w;
        *(float4*)&zS[wv][lane * 4] = z;
    }
    __syncthreads();
    for (int r = 0; r < 3; r++) {
        int j = r * 256 + tid;
        float acc[4];
        float bv = qb[j];
        #pragma unroll
        for (int t = 0; t < 4; t++) acc[t] = bv;
        const float* wrow = qW + (size_t)j * 256;
        for (int i = 0; i < 256; i += 4) {
            float4 wv4 = *(const float4*)&wrow[i];
            #pragma unroll
            for (int t = 0; t < 4; t++) acc[t] += dot4(*(const float4*)&zS[t][i], wv4);
        }
        #pragma unroll
        for (int t = 0; t < 4; t++) qkvbuf[(size_t)(b4 * 4 + t) * 768 + j] = acc[t];
    }
}

// ---------------------------------------------------------------------------
__global__ __launch_bounds__(64) void k_attn(const float* __restrict__ qkvbuf,
                                             float* __restrict__ obuf) {
    int blk = blockIdx.x;
    int b = blk >> 3, h = blk & 7;
    int tid = threadIdx.x;
    __shared__ float Ks[32 * 32], Vs[32 * 32];
    for (int idx = tid; idx < 1024; idx += 64) {
        int tk = idx >> 5, c = idx & 31;
        size_t qbase = ((size_t)(b * 32 + tk)) * 768 + h * 32 + c;
        Ks[idx] = qkvbuf[qbase + 256];
        Vs[idx] = qkvbuf[qbase + 512];
    }
    __syncthreads();
    if (tid < 32) {
        int tq = tid;
        float qv[32];
        size_t qb0 = ((size_t)(b * 32 + tq)) * 768 + h * 32;
        #pragma unroll
        for (int c = 0; c < 32; c++) qv[c] = qkvbuf[qb0 + c];
        float scr[32];
        float mx = -1e30f;
        #pragma unroll
        for (int tk = 0; tk < 32; tk++) {
            float dd = 0.f;
            #pragma unroll
            for (int c = 0; c < 32; c++) dd = fmaf(qv[c], Ks[tk * 32 + c], dd);
            dd *= 0.17677669529663687f;
            scr[tk] = dd;
            mx = fmaxf(mx, dd);
        }
        float sm = 0.f;
        #pragma unroll
        for (int tk = 0; tk < 32; tk++) { scr[tk] = __expf(scr[tk] - mx); sm += scr[tk]; }
        float inv = 1.f / sm;
        float o[32];
        #pragma unroll
        for (int c = 0; c < 32; c++) o[c] = 0.f;
        #pragma unroll
        for (int tk = 0; tk < 32; tk++) {
            float a = scr[tk] * inv;
            #pragma unroll
            for (int c = 0; c < 32; c++) o[c] = fmaf(a, Vs[tk * 32 + c], o[c]);
        }
        size_t ob = ((size_t)(b * 32 + tq)) * 256 + h * 32;
        #pragma unroll
        for (int c = 0; c < 32; c++) obuf[ob + c] = o[c];
    }
}

// ---------------------------------------------------------------------------
__global__ __launch_bounds__(256) void k_attn_out4(const float* __restrict__ obuf,
                                                   const float* __restrict__ W,
                                                   const float* __restrict__ bvec,
                                                   float* __restrict__ ybuf) {
    int b4 = blockIdx.x, tid = threadIdx.x;
    int lane = tid & 63, wv = tid >> 6;
    __shared__ float oS[4][256];
    *(float4*)&oS[wv][lane * 4] = *(const float4*)&obuf[(size_t)(b4 * 4 + wv) * 256 + lane * 4];
    __syncthreads();
    float acc[4];
    float bv = bvec[tid];
    #pragma unroll
    for (int t = 0; t < 4; t++) acc[t] = bv;
    const float* wrow = W + (size_t)tid * 256;
    for (int i = 0; i < 256; i += 4) {
        float4 wv4 = *(const float4*)&wrow[i];
        #pragma unroll
        for (int t = 0; t < 4; t++) acc[t] += dot4(*(const float4*)&oS[t][i], wv4);
    }
    #pragma unroll
    for (int t = 0; t < 4; t++) ybuf[(size_t)(b4 * 4 + t) * 256 + tid] += acc[t];
}

// ---------------------------------------------------------------------------
__global__ __launch_bounds__(256) void k_ff4(float* __restrict__ ybuf,
                                             const float* __restrict__ ln_s,
                                             const float* __restrict__ ln_b,
                                             const float* __restrict__ W1,
                                             const float* __restrict__ b1,
                                             const float* __restrict__ W2,
                                             const float* __restrict__ b2) {
    int b4 = blockIdx.x, tid = threadIdx.x;
    int lane = tid & 63, wv = tid >> 6;
    __shared__ float zS[4][256];
    __shared__ float fS[4][512];
    {
        int bt = b4 * 4 + wv;
        float4 yv = *(const float4*)&ybuf[(size_t)bt * 256 + lane * 4];
        float s = yv.x + yv.y + yv.z + yv.w;
        float s2 = yv.x * yv.x + yv.y * yv.y + yv.z * yv.z + yv.w * yv.w;
        #pragma unroll
        for (int off = 1; off < 64; off <<= 1) { s += __shfl_xor(s, off); s2 += __shfl_xor(s2, off); }
        float mu = s * (1.f / 256.f);
        float var = s2 * (1.f / 256.f) - mu * mu;
        float rstd = rsqrtf(var + 1e-5f);
        float4 ls = *(const float4*)&ln_s[lane * 4];
        float4 lb = *(const float4*)&ln_b[lane * 4];
        float4 z;
        z.x = (yv.x - mu) * rstd * ls.x + lb.x;
        z.y = (yv.y - mu) * rstd * ls.y + lb.y;
        z.z = (yv.z - mu) * rstd * ls.z + lb.z;
        z.w = (yv.w - mu) * rstd * ls.w + lb.w;
        *(float4*)&zS[wv][lane * 4] = z;
    }
    __syncthreads();
    for (int r = 0; r < 2; r++) {
        int j = r * 256 + tid;
        float acc[4];
        float bv = b1[j];
        #pragma unroll
        for (int t = 0; t < 4; t++) acc[t] = bv;
        const float* wrow = W1 + (size_t)j * 256;
        for (int i = 0; i < 256; i += 4) {
            float4 wv4 = *(const float4*)&wrow[i];
            #pragma unroll
            for (int t = 0; t < 4; t++) acc[t] += dot4(*(const float4*)&zS[t][i], wv4);
        }
        #pragma unroll
        for (int t = 0; t < 4; t++) fS[t][j] = fmaxf(acc[t], 0.f);
    }
    __syncthreads();
    float acc[4];
    float bv = b2[tid];
    #pragma unroll
    for (int t = 0; t < 4; t++) acc[t] = bv;
    const float* wrow = W2 + (size_t)tid * 512;
    for (int jj = 0; jj < 512; jj += 4) {
        float4 wv4 = *(const float4*)&wrow[jj];
        #pragma unroll
        for (int t = 0; t < 4; t++) acc[t] += dot4(*(const float4*)&fS[t][jj], wv4);
    }
    #pragma unroll
    for (int t = 0; t < 4; t++) {
        size_t idx = (size_t)(b4 * 4 + t) * 256 + tid;
        ybuf[idx] = ybuf[idx] + acc[t];
    }
}

// ---------------------------------------------------------------------------
__global__ __launch_bounds__(256) void k_pool_out(const float* __restrict__ ybuf,
                                                  const float* __restrict__ pW,
                                                  const float* __restrict__ pb,
                                                  const float* __restrict__ oW,
                                                  const float* __restrict__ ob,
                                                  const float* __restrict__ lns,
                                                  const float* __restrict__ lnb,
                                                  float* __restrict__ dout) {
    int b = blockIdx.x, tid = threadIdx.x;
    __shared__ float redP[256];
    __shared__ float wS[32];
    __shared__ float pS[256];
    __shared__ float red[8];
    int tq = tid >> 3, part = tid & 7;
    float partial = 0.f;
    {
        const float* yrow = ybuf + ((size_t)(b * 32 + tq)) * 256 + part * 32;
        const float* pwp = pW + part * 32;
        #pragma unroll
        for (int j = 0; j < 32; j += 4) {
            float4 yv = *(const float4*)&yrow[j];
            float4 wv = *(const float4*)&pwp[j];
            partial += dot4(yv, wv);
        }
    }
    redP[tid] = partial;
    __syncthreads();
    if (tid < 32) {
        float s = pb[0];
        for (int p = 0; p < 8; p++) s += redP[tid * 8 + p];
        float mx = s;
        #pragma unroll
        for (int off = 16; off; off >>= 1) mx = fmaxf(mx, __shfl_xor(mx, off));
        float e = __expf(s - mx);
        float sm = e;
        #pragma unroll
        for (int off = 16; off; off >>= 1) sm += __shfl_xor(sm, off);
        wS[tid] = e / sm;
    }
    __syncthreads();
    float p = 0.f;
    for (int t = 0; t < 32; t++) p += ybuf[((size_t)(b * 32 + t)) * 256 + tid] * wS[t];
    pS[tid] = p;
    __syncthreads();
    float accs[2];
    for (int r = 0; r < 2; r++) {
        int j = r * 256 + tid;
        float acc = ob[j];
        const float* wrow = oW + (size_t)j * 256;
        for (int g = 0; g < 256; g += 4) {
            float4 pv = *(const float4*)&pS[g];
            float4 wv = *(const float4*)&wrow[g];
            acc += dot4(pv, wv);
        }
        accs[r] = acc;
    }
    float s = accs[0] + accs[1];
    float s2 = accs[0] * accs[0] + accs[1] * accs[1];
    #pragma unroll
    for (int off = 32; off; off >>= 1) {
        s += __shfl_xor(s, off);
        s2 += __shfl_xor(s2, off);
    }
    int wid = threadIdx.x >> 6;
    int lane = threadIdx.x & 63;
    if (lane == 0) { red[wid] = s; red[4 + wid] = s2; }
    __syncthreads();
    s = red[0] + red[1] + red[2] + red[3];
    s2 = red[4] + red[5] + red[6] + red[7];
    float mu = s * (1.f / 512.f);
    float var = s2 * (1.f / 512.f) - mu * mu;
    float rstd = rsqrtf(var + 1e-5f);
    dout[b * 512 + tid]       = fmaxf((accs[0] - mu) * rstd * lns[tid] + lnb[tid], 0.f);
    dout[b * 512 + tid + 256] = fmaxf((accs[1] - mu) * rstd * lns[tid + 256] + lnb[tid + 256], 0.f);
}

// ---------------------------------------------------------------------------
extern "C" void kernel_launch(void* const* d_in, const int* in_sizes, int n_in,
                              void* d_out, int out_size, void* d_ws, size_t ws_size,
                              hipStream_t stream) {
    const float* drone_feats = (const float*)d_in[0];
    const float* boxes       = (const float*)d_in[1];
    const float* drone_mask  = (const float*)d_in[2];
    const float* in_proj_W   = (const float*)d_in[3];
    const float* in_proj_b   = (const float*)d_in[4];
    const float* gat_lin_W   = (const float*)d_in[5];
    const float* gat_edge_W  = (const float*)d_in[6];
    const float* gat_att_src = (const float*)d_in[7];
    const float* gat_att_dst = (const float*)d_in[8];
    const float* gat_att_edge= (const float*)d_in[9];
    const float* gat_bias    = (const float*)d_in[10];
    const float* gat_ln_s    = (const float*)d_in[11];
    const float* gat_ln_b    = (const float*)d_in[12];
    const float* temp_W      = (const float*)d_in[13];
    const float* temp_b      = (const float*)d_in[14];
    const float* pos_emb     = (const float*)d_in[15];
    const float* qkv_W       = (const float*)d_in[16];
    const float* qkv_b       = (const float*)d_in[17];
    const float* attn_out_W  = (const float*)d_in[18];
    const float* attn_out_b  = (const float*)d_in[19];
    const float* ln1_s       = (const float*)d_in[20];
    const float* ln1_b       = (const float*)d_in[21];
    const float* ln2_s       = (const float*)d_in[22];
    const float* ln2_b       = (const float*)d_in[23];
    const float* ff1_W       = (const float*)d_in[24];
    const float* ff1_b       = (const float*)d_in[25];
    const float* ff2_W       = (const float*)d_in[26];
    const float* ff2_b       = (const float*)d_in[27];
    const float* pool_W      = (const float*)d_in[28];
    const float* pool_b      = (const float*)d_in[29];
    const float* out_W       = (const float*)d_in[30];
    const float* out_b       = (const float*)d_in[31];
    const float* out_ln_s    = (const float*)d_in[32];
    const float* out_ln_b    = (const float*)d_in[33];
    float* out = (float*)d_out;

    float* ws = (float*)d_ws;
    float* xbuf = ws;
    size_t off = (size_t)BT * 64 * 256;
    unsigned short* Bsw = (unsigned short*)(ws + off); off += 4 * 16384 * 16 / 2;
    float* ybuf   = ws + off; off += (size_t)BT * 256;
    float* qkvbuf = ws + off; off += (size_t)BT * 768;
    float* obuf   = ws + off; off += (size_t)BT * 256;

    k_prep<<<dim3(256), dim3(256), 0, stream>>>(in_proj_W, gat_lin_W, Bsw);
    k_inproj<<<dim3(BT), dim3(256), 0, stream>>>(drone_feats, Bsw, in_proj_b, drone_mask, xbuf);
    for (int l = 0; l < 3; l++) {
        k_gat<<<dim3(BT), dim3(512), 0, stream>>>(xbuf, boxes, drone_mask,
            Bsw + (size_t)(1 + l) * 16384 * 16, gat_edge_W + (size_t)l * 768,
            gat_att_src + (size_t)l * 256, gat_att_dst + (size_t)l * 256,
            gat_att_edge + (size_t)l * 256, gat_bias + (size_t)l * 256,
            gat_ln_s + (size_t)l * 256, gat_ln_b + (size_t)l * 256);
    }
    k_frame_temp4<<<dim3(BT / 4), dim3(256), 0, stream>>>(xbuf, drone_mask, temp_W, temp_b, pos_emb, ybuf);
    for (int l = 0; l < 2; l++) {
        k_ln_qkv4<<<dim3(BT / 4), dim3(256), 0, stream>>>(ybuf, ln1_s + l * 256, ln1_b + l * 256,
            qkv_W + (size_t)l * 768 * 256, qkv_b + l * 768, qkvbuf);
        k_attn<<<dim3(512), dim3(64), 0, stream>>>(qkvbuf, obuf);
        k_attn_out4<<<dim3(BT / 4), dim3(256), 0, stream>>>(obuf,
            attn_out_W + (size_t)l * 65536, attn_out_b + l * 256, ybuf);
        k_ff4<<<dim3(BT / 4), dim3(256), 0, stream>>>(ybuf, ln2_s + l * 256, ln2_b + l * 256,
            ff1_W + (size_t)l * 131072, ff1_b + l * 512,
            ff2_W + (size_t)l * 131072, ff2_b + l * 256);
    }
    k_pool_out<<<dim3(64), dim3(256), 0, stream>>>(ybuf, pool_W, pool_b, out_W, out_b,
                                                   out_ln_s, out_ln_b, out);
}